// Round 7
// baseline (307.759 us; speedup 1.0000x reference)
//
#include <hip/hip_runtime.h>
#include <hip/hip_bf16.h>

// GraphTransformerLayer: B=8, N=1024, E=256, H=8, D=32, C=4 (all fp32 in/out)
#define BATCH 8
#define SEQ   1024
#define EMB   256
#define NH    8
#define HD    32
#define QSCALE 0.2550030053f   // log2(e)/sqrt(32), folded into Wq/bq

typedef __attribute__((ext_vector_type(8))) short short8;
typedef __attribute__((ext_vector_type(4))) float floatx4;

__device__ __forceinline__ ushort f2bf(float f) {
    __hip_bfloat16 h = __float2bfloat16(f);
    return *reinterpret_cast<ushort*>(&h);
}

__device__ __forceinline__ float bf2f(ushort u) {
    unsigned v = ((unsigned)u) << 16;
    return __builtin_bit_cast(float, v);
}

// async 16B/lane global->LDS DMA: each lane loads 16B from its own global
// address into wave-uniform LDS base + lane*16 (m97/m104 semantics).
__device__ __forceinline__ void gload_lds16(const float4* g, float4* l) {
    __builtin_amdgcn_global_load_lds(
        (const __attribute__((address_space(1))) unsigned int*)g,
        (__attribute__((address_space(3))) unsigned int*)l, 16, 0, 0);
}

// ---------------------------------------------------------------------------
// Kernel 0: prep — transpose Wq,Wk,Wv,Wo (fp32 [K][N]) to bf16 [N][K].
// Wq pre-scaled by log2(e)/sqrt(32). 256 blocks: matrix = blk/64, 8x8 tiles.
// ---------------------------------------------------------------------------
__global__ __launch_bounds__(256) void prep_kernel(
    const float* __restrict__ Wq, const float* __restrict__ Wk,
    const float* __restrict__ Wv, const float* __restrict__ Wo,
    ushort* __restrict__ Wqt, ushort* __restrict__ Wkt,
    ushort* __restrict__ Wvt, ushort* __restrict__ Wot)
{
    __shared__ float tilebuf[32][33];
    const int blk = blockIdx.x;
    const int mat = blk >> 6, tile = blk & 63;
    const int ti = tile >> 3, tj = tile & 7;     // ti: k-tile, tj: n-tile
    const float* W = (mat == 0) ? Wq : (mat == 1) ? Wk : (mat == 2) ? Wv : Wo;
    ushort* Wt = (mat == 0) ? Wqt : (mat == 1) ? Wkt : (mat == 2) ? Wvt : Wot;
    const float scale = (mat == 0) ? QSCALE : 1.0f;

    const int tx = threadIdx.x & 31, ty = threadIdx.x >> 5;  // 32 x 8
    #pragma unroll
    for (int p = 0; p < 4; ++p)
        tilebuf[ty + p * 8][tx] = W[(size_t)(ti * 32 + ty + p * 8) * EMB + tj * 32 + tx];
    __syncthreads();
    #pragma unroll
    for (int p = 0; p < 4; ++p)
        Wt[(size_t)(tj * 32 + ty + p * 8) * EMB + ti * 32 + tx] =
            f2bf(tilebuf[tx][ty + p * 8] * scale);
}

// ---------------------------------------------------------------------------
// Kernel 1: QKV projection as MFMA GEMM (grid (128,3), acc[16] — measured
// best shape). Q,K -> [B,H,N,D] bf16. V -> [B,H,D,Nperm] bf16 with
// quad-interleaved key slots (see attn header) so P^T feeds PV directly.
// ---------------------------------------------------------------------------
__global__ __launch_bounds__(256) void qkv_gemm(
    const float* __restrict__ x,
    const ushort* __restrict__ Wqt, const ushort* __restrict__ Wkt,
    const ushort* __restrict__ Wvt,
    const float* __restrict__ bq, const float* __restrict__ bk,
    const float* __restrict__ bv,
    ushort* __restrict__ Qb, ushort* __restrict__ Kb, ushort* __restrict__ Vt)
{
    const int mat = blockIdx.y;
    const ushort* __restrict__ Wt = (mat == 0) ? Wqt : (mat == 1) ? Wkt : Wvt;
    const float* __restrict__ bias = (mat == 0) ? bq : (mat == 1) ? bk : bv;
    const float bscale = (mat == 0) ? QSCALE : 1.0f;

    const int w = threadIdx.x >> 6, lane = threadIdx.x & 63;
    const int quad = lane >> 4, l16 = lane & 15;
    const int row0 = blockIdx.x * 64 + w * 16;

    floatx4 acc[16];
    #pragma unroll
    for (int i = 0; i < 16; ++i) acc[i] = (floatx4){0.f, 0.f, 0.f, 0.f};

    const float* __restrict__ xrow = x + (size_t)(row0 + l16) * EMB + quad * 8;

    #pragma unroll
    for (int ks = 0; ks < 8; ++ks) {
        const float4 xa0 = *(const float4*)(xrow + ks * 32);
        const float4 xa1 = *(const float4*)(xrow + ks * 32 + 4);
        ushort au[8] = {f2bf(xa0.x), f2bf(xa0.y), f2bf(xa0.z), f2bf(xa0.w),
                        f2bf(xa1.x), f2bf(xa1.y), f2bf(xa1.z), f2bf(xa1.w)};
        const short8 a = *(const short8*)au;
        #pragma unroll
        for (int i = 0; i < 16; ++i) {
            const short8 bf = *(const short8*)(Wt + (size_t)(i * 16 + l16) * EMB + ks * 32 + quad * 8);
            acc[i] = __builtin_amdgcn_mfma_f32_16x16x32_bf16(a, bf, acc[i], 0, 0, 0);
        }
    }

    const int gr0 = row0 + quad * 4;
    if (mat < 2) {
        ushort* __restrict__ dst = (mat == 0) ? Qb : Kb;
        #pragma unroll
        for (int i = 0; i < 16; ++i) {
            const int c = i * 16 + l16, h = c >> 5, d = c & (HD - 1);
            const float bb = bias[c] * bscale;
            #pragma unroll
            for (int r = 0; r < 4; ++r) {
                const int gr = gr0 + r, b = gr >> 10, n = gr & (SEQ - 1);
                dst[((size_t)(b * NH + h) * SEQ + n) * HD + d] = f2bf(acc[i][r] + bb);
            }
        }
    } else {
        const int b = gr0 >> 10, n0 = gr0 & (SEQ - 1);
        const int j0 = n0 & 31;
        const int slot = (j0 < 16) ? ((j0 >> 2) << 3)
                                   : ((((j0 - 16) >> 2) << 3) + 4);
        const int nperm = (n0 & ~31) | slot;
        #pragma unroll
        for (int i = 0; i < 16; ++i) {
            const int c = i * 16 + l16, h = c >> 5, d = c & (HD - 1);
            const float bb = bias[c];
            ushort4 t4;
            t4.x = f2bf(acc[i][0] + bb); t4.y = f2bf(acc[i][1] + bb);
            t4.z = f2bf(acc[i][2] + bb); t4.w = f2bf(acc[i][3] + bb);
            *(ushort4*)(Vt + ((size_t)(b * NH + h) * HD + d) * SEQ + nperm) = t4;
        }
    }
}

// ---------------------------------------------------------------------------
// Kernel 2: attention, swapped-QK^T — TWO HEADS PER WAVE.
// R6 showed attn immune to VALU/write reductions: the 512-thread 8-wave
// blocks fill the machine exactly (4/CU = wave cap), all blocks convoy in
// lockstep at each __syncthreads, and no pipe exceeds ~30%. This round keeps
// the FROZEN R1 barrier schedule (plain __syncthreads, depth-1 DMA dbuf,
// zero inline asm) but halves the block to 256 threads / 4 waves; wave w
// computes heads 2w and 2w+1:
//  - two independent dep chains per wave (2x ILP inside stall windows)
//  - adj LDS tile read ONCE per wave for both heads (LDS traffic halves)
//  - 4-wave rendezvous (less barrier skew)
// Work, traffic, numerics bit-identical. LDS 33280 B -> 4 blocks/CU,
// 16 waves/CU.
// ---------------------------------------------------------------------------
__global__ __launch_bounds__(256) void attn_kernel(
    const ushort* __restrict__ Qb, const ushort* __restrict__ Kb,
    const ushort* __restrict__ Vt, const float* __restrict__ adj,
    const float* __restrict__ Wa, const float* __restrict__ ba,
    ushort* __restrict__ cp, float* __restrict__ lsum)
{
    __shared__ float4 Atile[2][16][65];      // +1 float4 row pad (DMA fills [0,64))
    const int tid = threadIdx.x, w = tid >> 6, lane = tid & 63;
    const int quad = lane >> 4, l16 = lane & 15;
    const int h0 = 2 * w, h1 = 2 * w + 1;
    const int q0 = blockIdx.x * 16, b = blockIdx.y, z = blockIdx.z;
    const int bh0 = b * NH + h0, bh1 = b * NH + h1;
    const int kz = z * 512;

    const float LOG2E = 1.4426950408889634f;
    const float wa00 = Wa[0 * NH + h0] * LOG2E, wa01 = Wa[1 * NH + h0] * LOG2E;
    const float wa02 = Wa[2 * NH + h0] * LOG2E, wa03 = Wa[3 * NH + h0] * LOG2E;
    const float bah0 = ba[h0] * LOG2E;
    const float wa10 = Wa[0 * NH + h1] * LOG2E, wa11 = Wa[1 * NH + h1] * LOG2E;
    const float wa12 = Wa[2 * NH + h1] * LOG2E, wa13 = Wa[3 * NH + h1] * LOG2E;
    const float bah1 = ba[h1] * LOG2E;

    // Q frags (B-operand of swapped QK): rows = q0+l16, k = d
    const short8 aq0 = *(const short8*)(Qb + ((size_t)bh0 * SEQ + q0 + l16) * HD + quad * 8);
    const short8 aq1 = *(const short8*)(Qb + ((size_t)bh1 * SEQ + q0 + l16) * HD + quad * 8);

    floatx4 o00 = {0.f, 0.f, 0.f, 0.f}, o01 = {0.f, 0.f, 0.f, 0.f};
    floatx4 o10 = {0.f, 0.f, 0.f, 0.f}, o11 = {0.f, 0.f, 0.f, 0.f};
    float lacc0 = 0.f, lacc1 = 0.f;

    const float4* __restrict__ adjb = (const float4*)adj + (size_t)b * SEQ * SEQ;
    // wave w DMAs adj rows 4w .. 4w+3 of the block's 16-row tile
    const float4* asrc[4];
    #pragma unroll
    for (int p = 0; p < 4; ++p)
        asrc[p] = adjb + (size_t)(q0 + 4 * w + p) * SEQ + kz + lane;

    const ushort* __restrict__ Kb0 = Kb + (size_t)bh0 * SEQ * HD + (size_t)l16 * HD + quad * 8;
    const ushort* __restrict__ Kb1 = Kb + (size_t)bh1 * SEQ * HD + (size_t)l16 * HD + quad * 8;
    const ushort* __restrict__ Vb00 = Vt + ((size_t)bh0 * HD + l16) * SEQ + quad * 8;
    const ushort* __restrict__ Vb01 = Vt + ((size_t)bh0 * HD + 16 + l16) * SEQ + quad * 8;
    const ushort* __restrict__ Vb10 = Vt + ((size_t)bh1 * HD + l16) * SEQ + quad * 8;
    const ushort* __restrict__ Vb11 = Vt + ((size_t)bh1 * HD + 16 + l16) * SEQ + quad * 8;

    // prologue: DMA tile 0
    #pragma unroll
    for (int p = 0; p < 4; ++p)
        gload_lds16(asrc[p], &Atile[0][4 * w + p][0]);
    __syncthreads();   // implicit vmcnt(0) drain -> tile 0 resident

    for (int it = 0; it < 8; ++it) {          // 8 x 64 = 512 keys per split
        const int cur = it & 1;
        const int key0 = kz + it * 64;

        if (it < 7) {                          // async prefetch of next tile
            #pragma unroll
            for (int p = 0; p < 4; ++p)
                gload_lds16(asrc[p] + (it + 1) * 64, &Atile[cur ^ 1][4 * w + p][0]);
        }

        // K frags (A-operand): rows = keys, k = d — both heads
        const short8 k00 = *(const short8*)(Kb0 + (size_t)(key0)      * HD);
        const short8 k01 = *(const short8*)(Kb0 + (size_t)(key0 + 16) * HD);
        const short8 k02 = *(const short8*)(Kb0 + (size_t)(key0 + 32) * HD);
        const short8 k03 = *(const short8*)(Kb0 + (size_t)(key0 + 48) * HD);
        const short8 k10 = *(const short8*)(Kb1 + (size_t)(key0)      * HD);
        const short8 k11 = *(const short8*)(Kb1 + (size_t)(key0 + 16) * HD);
        const short8 k12 = *(const short8*)(Kb1 + (size_t)(key0 + 32) * HD);
        const short8 k13 = *(const short8*)(Kb1 + (size_t)(key0 + 48) * HD);
        const floatx4 zz = {0.f, 0.f, 0.f, 0.f};
        floatx4 s00 = __builtin_amdgcn_mfma_f32_16x16x32_bf16(k00, aq0, zz, 0, 0, 0);
        floatx4 s01 = __builtin_amdgcn_mfma_f32_16x16x32_bf16(k01, aq0, zz, 0, 0, 0);
        floatx4 s02 = __builtin_amdgcn_mfma_f32_16x16x32_bf16(k02, aq0, zz, 0, 0, 0);
        floatx4 s03 = __builtin_amdgcn_mfma_f32_16x16x32_bf16(k03, aq0, zz, 0, 0, 0);
        floatx4 s10 = __builtin_amdgcn_mfma_f32_16x16x32_bf16(k10, aq1, zz, 0, 0, 0);
        floatx4 s11 = __builtin_amdgcn_mfma_f32_16x16x32_bf16(k11, aq1, zz, 0, 0, 0);
        floatx4 s12 = __builtin_amdgcn_mfma_f32_16x16x32_bf16(k12, aq1, zz, 0, 0, 0);
        floatx4 s13 = __builtin_amdgcn_mfma_f32_16x16x32_bf16(k13, aq1, zz, 0, 0, 0);

        // bias + exp2; lane covers q = l16, keys = 16t + 4*quad + r.
        // adj tile read ONCE, used for BOTH heads' bias FMA chains.
        ushort pu00[8], pu01[8], pu10[8], pu11[8];
        #pragma unroll
        for (int r = 0; r < 4; ++r) {
            const int col = 4 * quad + r;
            const float4 a0 = Atile[cur][l16][col];
            const float4 a1 = Atile[cur][l16][16 + col];
            const float4 a2 = Atile[cur][l16][32 + col];
            const float4 a3 = Atile[cur][l16][48 + col];
            // head 0
            {
                const float b0 = fmaf(a0.x, wa00, fmaf(a0.y, wa01, fmaf(a0.z, wa02, fmaf(a0.w, wa03, bah0))));
                const float b1 = fmaf(a1.x, wa00, fmaf(a1.y, wa01, fmaf(a1.z, wa02, fmaf(a1.w, wa03, bah0))));
                const float b2 = fmaf(a2.x, wa00, fmaf(a2.y, wa01, fmaf(a2.z, wa02, fmaf(a2.w, wa03, bah0))));
                const float b3 = fmaf(a3.x, wa00, fmaf(a3.y, wa01, fmaf(a3.z, wa02, fmaf(a3.w, wa03, bah0))));
                const float p0 = __builtin_amdgcn_exp2f(s00[r] + b0);
                const float p1 = __builtin_amdgcn_exp2f(s01[r] + b1);
                const float p2 = __builtin_amdgcn_exp2f(s02[r] + b2);
                const float p3 = __builtin_amdgcn_exp2f(s03[r] + b3);
                lacc0 += (p0 + p1) + (p2 + p3);
                pu00[r] = f2bf(p0); pu00[4 + r] = f2bf(p1);
                pu01[r] = f2bf(p2); pu01[4 + r] = f2bf(p3);
            }
            // head 1
            {
                const float b0 = fmaf(a0.x, wa10, fmaf(a0.y, wa11, fmaf(a0.z, wa12, fmaf(a0.w, wa13, bah1))));
                const float b1 = fmaf(a1.x, wa10, fmaf(a1.y, wa11, fmaf(a1.z, wa12, fmaf(a1.w, wa13, bah1))));
                const float b2 = fmaf(a2.x, wa10, fmaf(a2.y, wa11, fmaf(a2.z, wa12, fmaf(a2.w, wa13, bah1))));
                const float b3 = fmaf(a3.x, wa10, fmaf(a3.y, wa11, fmaf(a3.z, wa12, fmaf(a3.w, wa13, bah1))));
                const float p0 = __builtin_amdgcn_exp2f(s10[r] + b0);
                const float p1 = __builtin_amdgcn_exp2f(s11[r] + b1);
                const float p2 = __builtin_amdgcn_exp2f(s12[r] + b2);
                const float p3 = __builtin_amdgcn_exp2f(s13[r] + b3);
                lacc1 += (p0 + p1) + (p2 + p3);
                pu10[r] = f2bf(p0); pu10[4 + r] = f2bf(p1);
                pu11[r] = f2bf(p2); pu11[4 + r] = f2bf(p3);
            }
        }
        const short8 pf00 = *(const short8*)pu00;
        const short8 pf01 = *(const short8*)pu01;
        const short8 pf10 = *(const short8*)pu10;
        const short8 pf11 = *(const short8*)pu11;

        // V frags (A-operand, quad-interleaved key slots match pf k-slots)
        const short8 v000 = *(const short8*)(Vb00 + key0);
        const short8 v010 = *(const short8*)(Vb01 + key0);
        const short8 v001 = *(const short8*)(Vb00 + key0 + 32);
        const short8 v011 = *(const short8*)(Vb01 + key0 + 32);
        o00 = __builtin_amdgcn_mfma_f32_16x16x32_bf16(v000, pf00, o00, 0, 0, 0);
        o01 = __builtin_amdgcn_mfma_f32_16x16x32_bf16(v010, pf00, o01, 0, 0, 0);
        o00 = __builtin_amdgcn_mfma_f32_16x16x32_bf16(v001, pf01, o00, 0, 0, 0);
        o01 = __builtin_amdgcn_mfma_f32_16x16x32_bf16(v011, pf01, o01, 0, 0, 0);
        const short8 v100 = *(const short8*)(Vb10 + key0);
        const short8 v110 = *(const short8*)(Vb11 + key0);
        const short8 v101 = *(const short8*)(Vb10 + key0 + 32);
        const short8 v111 = *(const short8*)(Vb11 + key0 + 32);
        o10 = __builtin_amdgcn_mfma_f32_16x16x32_bf16(v100, pf10, o10, 0, 0, 0);
        o11 = __builtin_amdgcn_mfma_f32_16x16x32_bf16(v110, pf10, o11, 0, 0, 0);
        o10 = __builtin_amdgcn_mfma_f32_16x16x32_bf16(v101, pf11, o10, 0, 0, 0);
        o11 = __builtin_amdgcn_mfma_f32_16x16x32_bf16(v111, pf11, o11, 0, 0, 0);

        __syncthreads();   // all waves done with Atile[cur]; next DMA arrived
    }

    // key dim is lane-local; only the quad (key-block) reduction remains
    lacc0 += __shfl_xor(lacc0, 16, 64);
    lacc0 += __shfl_xor(lacc0, 32, 64);
    lacc1 += __shfl_xor(lacc1, 16, 64);
    lacc1 += __shfl_xor(lacc1, 32, 64);

    ushort* __restrict__ cpz = cp + (size_t)z * BATCH * SEQ * EMB;
    float* __restrict__ lsz = lsum + (size_t)z * BATCH * SEQ * NH;
    const size_t grow = (size_t)b * SEQ + q0 + l16;
    ushort4 t;
    t.x = f2bf(o00[0]); t.y = f2bf(o00[1]); t.z = f2bf(o00[2]); t.w = f2bf(o00[3]);
    *(ushort4*)(cpz + grow * EMB + h0 * HD + 4 * quad)      = t;
    t.x = f2bf(o01[0]); t.y = f2bf(o01[1]); t.z = f2bf(o01[2]); t.w = f2bf(o01[3]);
    *(ushort4*)(cpz + grow * EMB + h0 * HD + 16 + 4 * quad) = t;
    t.x = f2bf(o10[0]); t.y = f2bf(o10[1]); t.z = f2bf(o10[2]); t.w = f2bf(o10[3]);
    *(ushort4*)(cpz + grow * EMB + h1 * HD + 4 * quad)      = t;
    t.x = f2bf(o11[0]); t.y = f2bf(o11[1]); t.z = f2bf(o11[2]); t.w = f2bf(o11[3]);
    *(ushort4*)(cpz + grow * EMB + h1 * HD + 16 + 4 * quad) = t;
    if (quad == 0) {
        lsz[grow * NH + h0] = lacc0;
        lsz[grow * NH + h1] = lacc1;
    }
}

// ---------------------------------------------------------------------------
// Kernel 3: outproj as MFMA GEMM. Combines the two bf16 key-split partials
// (fp32 add), normalizes by l, A-frags re-quantized bf16 inline, B-frags
// from transposed Wo. Epilogue: + bo + x residual. Grid (128,2).
// ---------------------------------------------------------------------------
__global__ __launch_bounds__(256) void outproj_gemm(
    const ushort* __restrict__ cp, const float* __restrict__ lsum,
    const ushort* __restrict__ Wot, const float* __restrict__ bo,
    const float* __restrict__ x, float* __restrict__ out)
{
    const int w = threadIdx.x >> 6, lane = threadIdx.x & 63;
    const int quad = lane >> 4, l16 = lane & 15;
    const int row0 = blockIdx.x * 64 + w * 16;
    const int c0 = blockIdx.y * 128;     // column half
    const int arow = row0 + l16;
    const ushort* __restrict__ cp1 = cp + (size_t)BATCH * SEQ * EMB;
    const float* __restrict__ l1  = lsum + (size_t)BATCH * SEQ * NH;

    floatx4 acc[8];
    #pragma unroll
    for (int i = 0; i < 8; ++i) acc[i] = (floatx4){0.f, 0.f, 0.f, 0.f};

    #pragma unroll
    for (int ks = 0; ks < 8; ++ks) {
        const float invl = 1.0f / (lsum[(size_t)arow * NH + ks] + l1[(size_t)arow * NH + ks]);
        const size_t cb = (size_t)arow * EMB + ks * 32 + quad * 8;
        const ushort4 c00 = *(const ushort4*)(cp + cb);
        const ushort4 c01 = *(const ushort4*)(cp + cb + 4);
        const ushort4 c10 = *(const ushort4*)(cp1 + cb);
        const ushort4 c11 = *(const ushort4*)(cp1 + cb + 4);
        ushort au[8] = {
            f2bf((bf2f(c00.x) + bf2f(c10.x)) * invl),
            f2bf((bf2f(c00.y) + bf2f(c10.y)) * invl),
            f2bf((bf2f(c00.z) + bf2f(c10.z)) * invl),
            f2bf((bf2f(c00.w) + bf2f(c10.w)) * invl),
            f2bf((bf2f(c01.x) + bf2f(c11.x)) * invl),
            f2bf((bf2f(c01.y) + bf2f(c11.y)) * invl),
            f2bf((bf2f(c01.z) + bf2f(c11.z)) * invl),
            f2bf((bf2f(c01.w) + bf2f(c11.w)) * invl)};
        const short8 a = *(const short8*)au;
        #pragma unroll
        for (int i = 0; i < 8; ++i) {
            const short8 bfr = *(const short8*)(Wot + (size_t)(c0 + i * 16 + l16) * EMB + ks * 32 + quad * 8);
            acc[i] = __builtin_amdgcn_mfma_f32_16x16x32_bf16(a, bfr, acc[i], 0, 0, 0);
        }
    }

    const int gr0 = row0 + quad * 4;
    #pragma unroll
    for (int i = 0; i < 8; ++i) {
        const int c = c0 + i * 16 + l16;
        const float bov = bo[c];
        #pragma unroll
        for (int r = 0; r < 4; ++r) {
            const size_t idx = (size_t)(gr0 + r) * EMB + c;
            out[idx] = acc[i][r] + bov + x[idx];
        }
    }
}

extern "C" void kernel_launch(void* const* d_in, const int* in_sizes, int n_in,
                              void* d_out, int out_size, void* d_ws, size_t ws_size,
                              hipStream_t stream) {
    const float* x   = (const float*)d_in[0];
    const float* adj = (const float*)d_in[1];
    const float* Wq  = (const float*)d_in[2];
    const float* bq  = (const float*)d_in[3];
    const float* Wk  = (const float*)d_in[4];
    const float* bk  = (const float*)d_in[5];
    const float* Wv  = (const float*)d_in[6];
    const float* bv  = (const float*)d_in[7];
    const float* Wo  = (const float*)d_in[8];
    const float* bo  = (const float*)d_in[9];
    const float* Wa  = (const float*)d_in[10];
    const float* ba  = (const float*)d_in[11];

    const size_t per = (size_t)BATCH * NH * SEQ * HD;   // 2,097,152
    ushort* Qb  = (ushort*)d_ws;
    ushort* Kb  = Qb + per;
    ushort* Vt  = Kb + per;
    ushort* Wqt = Vt + per;
    ushort* Wkt = Wqt + EMB * EMB;
    ushort* Wvt = Wkt + EMB * EMB;
    ushort* Wot = Wvt + EMB * EMB;
    ushort* cpw = Wot + EMB * EMB;                      // 2 x 4 MB bf16
    float*  ls  = (float*)(cpw + 2 * (size_t)BATCH * SEQ * EMB);  // 2 x 256 KB

    prep_kernel<<<256, 256, 0, stream>>>(Wq, Wk, Wv, Wo, Wqt, Wkt, Wvt, Wot);
    qkv_gemm<<<dim3(BATCH * SEQ / 64, 3), 256, 0, stream>>>(
        x, Wqt, Wkt, Wvt, bq, bk, bv, Qb, Kb, Vt);
    attn_kernel<<<dim3(SEQ / 16, BATCH, 2), 256, 0, stream>>>(
        Qb, Kb, Vt, adj, Wa, ba, cpw, ls);
    outproj_gemm<<<dim3(BATCH * SEQ / 64, 2), 256, 0, stream>>>(
        cpw, ls, Wot, bo, x, (float*)d_out);
}

// Round 8
// 285.942 us; speedup vs baseline: 1.0763x; 1.0763x over previous
//
#include <hip/hip_runtime.h>
#include <hip/hip_bf16.h>

// GraphTransformerLayer: B=8, N=1024, E=256, H=8, D=32, C=4 (all fp32 in/out)
#define BATCH 8
#define SEQ   1024
#define EMB   256
#define NH    8
#define HD    32
#define QSCALE 0.2550030053f   // log2(e)/sqrt(32), folded into Wq/bq

typedef __attribute__((ext_vector_type(8))) short short8;
typedef __attribute__((ext_vector_type(4))) float floatx4;

__device__ __forceinline__ ushort f2bf(float f) {
    __hip_bfloat16 h = __float2bfloat16(f);
    return *reinterpret_cast<ushort*>(&h);
}

__device__ __forceinline__ float bf2f(ushort u) {
    unsigned v = ((unsigned)u) << 16;
    return __builtin_bit_cast(float, v);
}

// async 16B/lane global->LDS DMA: each lane loads 16B from its own global
// address into wave-uniform LDS base + lane*16 (m97/m104 semantics).
__device__ __forceinline__ void gload_lds16(const float4* g, float4* l) {
    __builtin_amdgcn_global_load_lds(
        (const __attribute__((address_space(1))) unsigned int*)g,
        (__attribute__((address_space(3))) unsigned int*)l, 16, 0, 0);
}

// ---------------------------------------------------------------------------
// Kernel 0: prep — transpose Wq,Wk,Wv,Wo (fp32 [K][N]) to bf16 [N][K].
// Wq pre-scaled by log2(e)/sqrt(32). 256 blocks: matrix = blk/64, 8x8 tiles.
// ---------------------------------------------------------------------------
__global__ __launch_bounds__(256) void prep_kernel(
    const float* __restrict__ Wq, const float* __restrict__ Wk,
    const float* __restrict__ Wv, const float* __restrict__ Wo,
    ushort* __restrict__ Wqt, ushort* __restrict__ Wkt,
    ushort* __restrict__ Wvt, ushort* __restrict__ Wot)
{
    __shared__ float tilebuf[32][33];
    const int blk = blockIdx.x;
    const int mat = blk >> 6, tile = blk & 63;
    const int ti = tile >> 3, tj = tile & 7;     // ti: k-tile, tj: n-tile
    const float* W = (mat == 0) ? Wq : (mat == 1) ? Wk : (mat == 2) ? Wv : Wo;
    ushort* Wt = (mat == 0) ? Wqt : (mat == 1) ? Wkt : (mat == 2) ? Wvt : Wot;
    const float scale = (mat == 0) ? QSCALE : 1.0f;

    const int tx = threadIdx.x & 31, ty = threadIdx.x >> 5;  // 32 x 8
    #pragma unroll
    for (int p = 0; p < 4; ++p)
        tilebuf[ty + p * 8][tx] = W[(size_t)(ti * 32 + ty + p * 8) * EMB + tj * 32 + tx];
    __syncthreads();
    #pragma unroll
    for (int p = 0; p < 4; ++p)
        Wt[(size_t)(tj * 32 + ty + p * 8) * EMB + ti * 32 + tx] =
            f2bf(tilebuf[tx][ty + p * 8] * scale);
}

// ---------------------------------------------------------------------------
// Kernel 1: QKV projection as MFMA GEMM (grid (128,3), acc[16]).
// NEW: outputs written in MFMA-FRAG-PACKED layouts so every attn global load
// is base + lane*16B (fully coalesced). R7 analysis: attn's old K loads
// (stride 64B across l16) and V loads (stride 2KB) touched 16 cache lines
// PER INSTRUCTION -> TA/TD address-processing bound (invisible in
// VALU/MFMA/HBM counters). Layouts:
//   Q,K: [bh][n/16][d/8][n%16][d%8]          (512 elems per 16-row tile)
//   V:   [bh][key/32][d/16][sg][d%16][si]    (1024 elems per 32-key tile)
// where slot(j0) = sg*8+si encodes the quad-interleaved key order that the
// swapped-QK^T P^T fragment produces: j0<16: sg=j0>>2, si=j0&3;
// j0>=16: sg=(j0-16)>>2, si=4+(j0&3). Frag semantics identical to before.
// ---------------------------------------------------------------------------
__global__ __launch_bounds__(256) void qkv_gemm(
    const float* __restrict__ x,
    const ushort* __restrict__ Wqt, const ushort* __restrict__ Wkt,
    const ushort* __restrict__ Wvt,
    const float* __restrict__ bq, const float* __restrict__ bk,
    const float* __restrict__ bv,
    ushort* __restrict__ Qb, ushort* __restrict__ Kb, ushort* __restrict__ Vt)
{
    const int mat = blockIdx.y;
    const ushort* __restrict__ Wt = (mat == 0) ? Wqt : (mat == 1) ? Wkt : Wvt;
    const float* __restrict__ bias = (mat == 0) ? bq : (mat == 1) ? bk : bv;
    const float bscale = (mat == 0) ? QSCALE : 1.0f;

    const int w = threadIdx.x >> 6, lane = threadIdx.x & 63;
    const int quad = lane >> 4, l16 = lane & 15;
    const int row0 = blockIdx.x * 64 + w * 16;

    floatx4 acc[16];
    #pragma unroll
    for (int i = 0; i < 16; ++i) acc[i] = (floatx4){0.f, 0.f, 0.f, 0.f};

    const float* __restrict__ xrow = x + (size_t)(row0 + l16) * EMB + quad * 8;

    #pragma unroll
    for (int ks = 0; ks < 8; ++ks) {
        const float4 xa0 = *(const float4*)(xrow + ks * 32);
        const float4 xa1 = *(const float4*)(xrow + ks * 32 + 4);
        ushort au[8] = {f2bf(xa0.x), f2bf(xa0.y), f2bf(xa0.z), f2bf(xa0.w),
                        f2bf(xa1.x), f2bf(xa1.y), f2bf(xa1.z), f2bf(xa1.w)};
        const short8 a = *(const short8*)au;
        #pragma unroll
        for (int i = 0; i < 16; ++i) {
            const short8 bf = *(const short8*)(Wt + (size_t)(i * 16 + l16) * EMB + ks * 32 + quad * 8);
            acc[i] = __builtin_amdgcn_mfma_f32_16x16x32_bf16(a, bf, acc[i], 0, 0, 0);
        }
    }

    const int gr0 = row0 + quad * 4;
    if (mat < 2) {
        ushort* __restrict__ dst = (mat == 0) ? Qb : Kb;
        #pragma unroll
        for (int i = 0; i < 16; ++i) {
            const int c = i * 16 + l16, h = c >> 5, d = c & (HD - 1);
            const float bb = bias[c] * bscale;
            #pragma unroll
            for (int r = 0; r < 4; ++r) {
                const int gr = gr0 + r, b = gr >> 10, n = gr & (SEQ - 1);
                // packed: [bh][n>>4][d>>3][n&15][d&7]
                dst[(size_t)(b * NH + h) * SEQ * HD + (size_t)(n >> 4) * 512
                    + (d >> 3) * 128 + (n & 15) * 8 + (d & 7)] = f2bf(acc[i][r] + bb);
            }
        }
    } else {
        const int b = gr0 >> 10, n0 = gr0 & (SEQ - 1);
        const int keyblk = n0 >> 5, j0 = n0 & 31;
        const int sg = (j0 & 15) >> 2, si0 = (j0 & 16) ? 4 : 0;
        #pragma unroll
        for (int i = 0; i < 16; ++i) {
            const int c = i * 16 + l16, h = c >> 5, d = c & (HD - 1);
            const float bb = bias[c];
            ushort4 t4;
            t4.x = f2bf(acc[i][0] + bb); t4.y = f2bf(acc[i][1] + bb);
            t4.z = f2bf(acc[i][2] + bb); t4.w = f2bf(acc[i][3] + bb);
            // packed: [bh][keyblk][d>>4][sg][d&15][si0..si0+3]
            *(ushort4*)(Vt + (size_t)(b * NH + h) * SEQ * HD + (size_t)keyblk * 1024
                        + (d >> 4) * 512 + sg * 128 + (d & 15) * 8 + si0) = t4;
        }
    }
}

// ---------------------------------------------------------------------------
// Kernel 2: attention, swapped-QK^T — R6 structure (512 thr, one head/wave,
// plain __syncthreads, depth-1 DMA dbuf — all schedule variants measured
// slower; R7's 2-heads/wave also slower). NEW this round: Q/K/V read from
// the frag-packed layouts -> every global load is base + lane*8 elems
// (1KB contiguous per wave instruction, was 16 cache lines each).
// LDS 2*16*65*16 = 33280 B -> 4 blocks/CU.
// ---------------------------------------------------------------------------
__global__ __launch_bounds__(512) void attn_kernel(
    const ushort* __restrict__ Qb, const ushort* __restrict__ Kb,
    const ushort* __restrict__ Vt, const float* __restrict__ adj,
    const float* __restrict__ Wa, const float* __restrict__ ba,
    ushort* __restrict__ cp, float* __restrict__ lsum)
{
    __shared__ float4 Atile[2][16][65];      // +1 float4 row pad (DMA fills [0,64))
    const int tid = threadIdx.x, h = tid >> 6, lane = tid & 63;
    const int quad = lane >> 4, l16 = lane & 15;
    const int q0 = blockIdx.x * 16, b = blockIdx.y, z = blockIdx.z;
    const int bh = b * NH + h;
    const int kz = z * 512;

    const float LOG2E = 1.4426950408889634f;
    const float wa0 = Wa[0 * NH + h] * LOG2E, wa1 = Wa[1 * NH + h] * LOG2E;
    const float wa2 = Wa[2 * NH + h] * LOG2E, wa3 = Wa[3 * NH + h] * LOG2E;
    const float bah = ba[h] * LOG2E;

    // Q frag (B-operand of swapped QK), packed: one coalesced 1KB wave load
    const short8 aq = *(const short8*)(Qb + (size_t)bh * SEQ * HD
                                      + (size_t)blockIdx.x * 512 + lane * 8);

    floatx4 o0 = {0.f, 0.f, 0.f, 0.f}, o1 = {0.f, 0.f, 0.f, 0.f};
    float lacc = 0.f;

    const float4* __restrict__ adjb = (const float4*)adj + (size_t)b * SEQ * SEQ;
    // wave h DMAs adj rows 2h and 2h+1 of the block's 16-row tile
    const float4* __restrict__ asrc0 = adjb + (size_t)(q0 + 2 * h)     * SEQ + kz + lane;
    const float4* __restrict__ asrc1 = adjb + (size_t)(q0 + 2 * h + 1) * SEQ + kz + lane;

    const ushort* __restrict__ Kbase = Kb + (size_t)bh * SEQ * HD + lane * 8;
    const ushort* __restrict__ Vbase = Vt + (size_t)bh * SEQ * HD + lane * 8;

    // prologue: DMA tile 0
    gload_lds16(asrc0, &Atile[0][2 * h][0]);
    gload_lds16(asrc1, &Atile[0][2 * h + 1][0]);
    __syncthreads();   // implicit vmcnt(0) drain -> tile 0 resident

    for (int it = 0; it < 8; ++it) {          // 8 x 64 = 512 keys per split
        const int cur = it & 1;
        const int key0 = kz + it * 64;

        if (it < 7) {                          // async prefetch of next tile
            gload_lds16(asrc0 + (it + 1) * 64, &Atile[cur ^ 1][2 * h][0]);
            gload_lds16(asrc1 + (it + 1) * 64, &Atile[cur ^ 1][2 * h + 1][0]);
        }

        // K frags (A-operand), packed: 4 consecutive 1KB coalesced loads
        const ushort* kp = Kbase + (size_t)(key0 >> 4) * 512;
        const short8 k0 = *(const short8*)(kp);
        const short8 k1 = *(const short8*)(kp + 512);
        const short8 k2 = *(const short8*)(kp + 1024);
        const short8 k3 = *(const short8*)(kp + 1536);
        const floatx4 zz = {0.f, 0.f, 0.f, 0.f};
        floatx4 s0 = __builtin_amdgcn_mfma_f32_16x16x32_bf16(k0, aq, zz, 0, 0, 0);
        floatx4 s1 = __builtin_amdgcn_mfma_f32_16x16x32_bf16(k1, aq, zz, 0, 0, 0);
        floatx4 s2 = __builtin_amdgcn_mfma_f32_16x16x32_bf16(k2, aq, zz, 0, 0, 0);
        floatx4 s3 = __builtin_amdgcn_mfma_f32_16x16x32_bf16(k3, aq, zz, 0, 0, 0);

        // bias + exp2; lane covers q = l16, keys = 16t + 4*quad + r.
        ushort pu0[8], pu1[8];
        #pragma unroll
        for (int r = 0; r < 4; ++r) {
            const int col = 4 * quad + r;
            const float4 a0 = Atile[cur][l16][col];
            const float4 a1 = Atile[cur][l16][16 + col];
            const float4 a2 = Atile[cur][l16][32 + col];
            const float4 a3 = Atile[cur][l16][48 + col];
            const float b0 = fmaf(a0.x, wa0, fmaf(a0.y, wa1, fmaf(a0.z, wa2, fmaf(a0.w, wa3, bah))));
            const float b1 = fmaf(a1.x, wa0, fmaf(a1.y, wa1, fmaf(a1.z, wa2, fmaf(a1.w, wa3, bah))));
            const float b2 = fmaf(a2.x, wa0, fmaf(a2.y, wa1, fmaf(a2.z, wa2, fmaf(a2.w, wa3, bah))));
            const float b3 = fmaf(a3.x, wa0, fmaf(a3.y, wa1, fmaf(a3.z, wa2, fmaf(a3.w, wa3, bah))));
            const float p0 = __builtin_amdgcn_exp2f(s0[r] + b0);
            const float p1 = __builtin_amdgcn_exp2f(s1[r] + b1);
            const float p2 = __builtin_amdgcn_exp2f(s2[r] + b2);
            const float p3 = __builtin_amdgcn_exp2f(s3[r] + b3);
            lacc += (p0 + p1) + (p2 + p3);
            pu0[r]     = f2bf(p0);   // k-slot 8*quad+r     -> key 16*0+4q+r
            pu0[4 + r] = f2bf(p1);   // k-slot 8*quad+4+r   -> key 16*1+4q+r
            pu1[r]     = f2bf(p2);   // same, keys +32
            pu1[4 + r] = f2bf(p3);   // same, keys +48
        }
        const short8 pf0 = *(const short8*)pu0;
        const short8 pf1 = *(const short8*)pu1;

        // V frags (A-operand), packed: 4 consecutive 1KB coalesced loads
        const ushort* vp = Vbase + (size_t)(key0 >> 5) * 1024;
        const short8 v00 = *(const short8*)(vp);          // d=l16,    keys blk0
        const short8 v10 = *(const short8*)(vp + 512);    // d=16+l16, keys blk0
        const short8 v01 = *(const short8*)(vp + 1024);   // d=l16,    keys blk1
        const short8 v11 = *(const short8*)(vp + 1536);   // d=16+l16, keys blk1
        o0 = __builtin_amdgcn_mfma_f32_16x16x32_bf16(v00, pf0, o0, 0, 0, 0);
        o1 = __builtin_amdgcn_mfma_f32_16x16x32_bf16(v10, pf0, o1, 0, 0, 0);
        o0 = __builtin_amdgcn_mfma_f32_16x16x32_bf16(v01, pf1, o0, 0, 0, 0);
        o1 = __builtin_amdgcn_mfma_f32_16x16x32_bf16(v11, pf1, o1, 0, 0, 0);

        __syncthreads();   // all waves done with Atile[cur]; next DMA arrived
    }

    // key dim is lane-local; only the quad (key-block) reduction remains
    lacc += __shfl_xor(lacc, 16, 64);
    lacc += __shfl_xor(lacc, 32, 64);

    ushort* __restrict__ cpz = cp + (size_t)z * BATCH * SEQ * EMB;
    float* __restrict__ lsz = lsum + (size_t)z * BATCH * SEQ * NH;
    const size_t grow = (size_t)b * SEQ + q0 + l16;
    // lane holds partial ctx[d = 4*quad + r (+16)][q = l16]; store bf16
    ushort4 t0, t1;
    t0.x = f2bf(o0[0]); t0.y = f2bf(o0[1]); t0.z = f2bf(o0[2]); t0.w = f2bf(o0[3]);
    t1.x = f2bf(o1[0]); t1.y = f2bf(o1[1]); t1.z = f2bf(o1[2]); t1.w = f2bf(o1[3]);
    *(ushort4*)(cpz + grow * EMB + h * HD + 4 * quad)      = t0;
    *(ushort4*)(cpz + grow * EMB + h * HD + 16 + 4 * quad) = t1;
    if (quad == 0) lsz[grow * NH + h] = lacc;
}

// ---------------------------------------------------------------------------
// Kernel 3: outproj as MFMA GEMM. Combines the two bf16 key-split partials
// (fp32 add), normalizes by l, A-frags re-quantized bf16 inline, B-frags
// from transposed Wo. Epilogue: + bo + x residual. Grid (128,2).
// ---------------------------------------------------------------------------
__global__ __launch_bounds__(256) void outproj_gemm(
    const ushort* __restrict__ cp, const float* __restrict__ lsum,
    const ushort* __restrict__ Wot, const float* __restrict__ bo,
    const float* __restrict__ x, float* __restrict__ out)
{
    const int w = threadIdx.x >> 6, lane = threadIdx.x & 63;
    const int quad = lane >> 4, l16 = lane & 15;
    const int row0 = blockIdx.x * 64 + w * 16;
    const int c0 = blockIdx.y * 128;     // column half
    const int arow = row0 + l16;
    const ushort* __restrict__ cp1 = cp + (size_t)BATCH * SEQ * EMB;
    const float* __restrict__ l1  = lsum + (size_t)BATCH * SEQ * NH;

    floatx4 acc[8];
    #pragma unroll
    for (int i = 0; i < 8; ++i) acc[i] = (floatx4){0.f, 0.f, 0.f, 0.f};

    #pragma unroll
    for (int ks = 0; ks < 8; ++ks) {
        const float invl = 1.0f / (lsum[(size_t)arow * NH + ks] + l1[(size_t)arow * NH + ks]);
        const size_t cb = (size_t)arow * EMB + ks * 32 + quad * 8;
        const ushort4 c00 = *(const ushort4*)(cp + cb);
        const ushort4 c01 = *(const ushort4*)(cp + cb + 4);
        const ushort4 c10 = *(const ushort4*)(cp1 + cb);
        const ushort4 c11 = *(const ushort4*)(cp1 + cb + 4);
        ushort au[8] = {
            f2bf((bf2f(c00.x) + bf2f(c10.x)) * invl),
            f2bf((bf2f(c00.y) + bf2f(c10.y)) * invl),
            f2bf((bf2f(c00.z) + bf2f(c10.z)) * invl),
            f2bf((bf2f(c00.w) + bf2f(c10.w)) * invl),
            f2bf((bf2f(c01.x) + bf2f(c11.x)) * invl),
            f2bf((bf2f(c01.y) + bf2f(c11.y)) * invl),
            f2bf((bf2f(c01.z) + bf2f(c11.z)) * invl),
            f2bf((bf2f(c01.w) + bf2f(c11.w)) * invl)};
        const short8 a = *(const short8*)au;
        #pragma unroll
        for (int i = 0; i < 8; ++i) {
            const short8 bfr = *(const short8*)(Wot + (size_t)(c0 + i * 16 + l16) * EMB + ks * 32 + quad * 8);
            acc[i] = __builtin_amdgcn_mfma_f32_16x16x32_bf16(a, bfr, acc[i], 0, 0, 0);
        }
    }

    const int gr0 = row0 + quad * 4;
    #pragma unroll
    for (int i = 0; i < 8; ++i) {
        const int c = c0 + i * 16 + l16;
        const float bov = bo[c];
        #pragma unroll
        for (int r = 0; r < 4; ++r) {
            const size_t idx = (size_t)(gr0 + r) * EMB + c;
            out[idx] = acc[i][r] + bov + x[idx];
        }
    }
}

extern "C" void kernel_launch(void* const* d_in, const int* in_sizes, int n_in,
                              void* d_out, int out_size, void* d_ws, size_t ws_size,
                              hipStream_t stream) {
    const float* x   = (const float*)d_in[0];
    const float* adj = (const float*)d_in[1];
    const float* Wq  = (const float*)d_in[2];
    const float* bq  = (const float*)d_in[3];
    const float* Wk  = (const float*)d_in[4];
    const float* bk  = (const float*)d_in[5];
    const float* Wv  = (const float*)d_in[6];
    const float* bv  = (const float*)d_in[7];
    const float* Wo  = (const float*)d_in[8];
    const float* bo  = (const float*)d_in[9];
    const float* Wa  = (const float*)d_in[10];
    const float* ba  = (const float*)d_in[11];

    const size_t per = (size_t)BATCH * NH * SEQ * HD;   // 2,097,152
    ushort* Qb  = (ushort*)d_ws;
    ushort* Kb  = Qb + per;
    ushort* Vt  = Kb + per;
    ushort* Wqt = Vt + per;
    ushort* Wkt = Wqt + EMB * EMB;
    ushort* Wvt = Wkt + EMB * EMB;
    ushort* Wot = Wvt + EMB * EMB;
    ushort* cpw = Wot + EMB * EMB;                      // 2 x 4 MB bf16
    float*  ls  = (float*)(cpw + 2 * (size_t)BATCH * SEQ * EMB);  // 2 x 256 KB

    prep_kernel<<<256, 256, 0, stream>>>(Wq, Wk, Wv, Wo, Wqt, Wkt, Wvt, Wot);
    qkv_gemm<<<dim3(BATCH * SEQ / 64, 3), 256, 0, stream>>>(
        x, Wqt, Wkt, Wvt, bq, bk, bv, Qb, Kb, Vt);
    attn_kernel<<<dim3(SEQ / 16, BATCH, 2), 512, 0, stream>>>(
        Qb, Kb, Vt, adj, Wa, ba, cpw, ls);
    outproj_gemm<<<dim3(BATCH * SEQ / 64, 2), 256, 0, stream>>>(
        cpw, ls, Wot, bo, x, (float*)d_out);
}

// Round 9
// 276.005 us; speedup vs baseline: 1.1150x; 1.0360x over previous
//
#include <hip/hip_runtime.h>
#include <hip/hip_bf16.h>

// GraphTransformerLayer: B=8, N=1024, E=256, H=8, D=32, C=4 (all fp32 in/out)
#define BATCH 8
#define SEQ   1024
#define EMB   256
#define NH    8
#define HD    32
#define QSCALE 0.2550030053f   // log2(e)/sqrt(32), folded into Wq/bq

typedef __attribute__((ext_vector_type(8))) short short8;
typedef __attribute__((ext_vector_type(4))) float floatx4;

__device__ __forceinline__ ushort f2bf(float f) {
    __hip_bfloat16 h = __float2bfloat16(f);
    return *reinterpret_cast<ushort*>(&h);
}

__device__ __forceinline__ float bf2f(ushort u) {
    unsigned v = ((unsigned)u) << 16;
    return __builtin_bit_cast(float, v);
}

// async 16B/lane global->LDS DMA: each lane loads 16B from its own global
// address into wave-uniform LDS base + lane*16 (m97/m104 semantics).
__device__ __forceinline__ void gload_lds16(const float4* g, float4* l) {
    __builtin_amdgcn_global_load_lds(
        (const __attribute__((address_space(1))) unsigned int*)g,
        (__attribute__((address_space(3))) unsigned int*)l, 16, 0, 0);
}

// ---------------------------------------------------------------------------
// Frag-packed layouts (R8 lesson: 16-lines-per-instruction address divergence
// was the invisible bottleneck; every GEMM operand now loads base + lane*8):
//   W (all 4):  [c/16][ks][quad][l16][8]   elem (c,k): (c>>4)*4096 + (k>>5)*512
//                                          + ((k>>3)&3)*128 + (c&15)*8 + (k&7)
//   x packed:   [n/16][ks][quad][l16][8]   same formula with (n,k)
//   Q,K:        [bh][n/16][d/8][n%16][d%8]
//   V:          [bh][key/32][d/16][sg][d%16][si]  (quad-interleaved slots)
//   cp:         [tile=n/16][h][l16=n%16][d%32]    (1KB contiguous per wave)
// ---------------------------------------------------------------------------

// Kernel 0: prep. blocks 0..255: transpose+pack Wq,Wk,Wv,Wo (Wq pre-scaled
// by log2(e)/sqrt(32)). blocks 256..767: pack x -> bf16 frag layout.
__global__ __launch_bounds__(256) void prep_kernel(
    const float* __restrict__ Wq, const float* __restrict__ Wk,
    const float* __restrict__ Wv, const float* __restrict__ Wo,
    const float* __restrict__ x,
    ushort* __restrict__ Wqt, ushort* __restrict__ Wkt,
    ushort* __restrict__ Wvt, ushort* __restrict__ Wot,
    ushort* __restrict__ xb)
{
    const int blk = blockIdx.x;
    if (blk < 256) {
        __shared__ float tilebuf[32][33];
        const int mat = blk >> 6, tile = blk & 63;
        const int ti = tile >> 3, tj = tile & 7;     // ti: k-tile, tj: n-tile
        const float* W = (mat == 0) ? Wq : (mat == 1) ? Wk : (mat == 2) ? Wv : Wo;
        ushort* Wt = (mat == 0) ? Wqt : (mat == 1) ? Wkt : (mat == 2) ? Wvt : Wot;
        const float scale = (mat == 0) ? QSCALE : 1.0f;

        const int tx = threadIdx.x & 31, ty = threadIdx.x >> 5;  // 32 x 8
        #pragma unroll
        for (int p = 0; p < 4; ++p)
            tilebuf[ty + p * 8][tx] = W[(size_t)(ti * 32 + ty + p * 8) * EMB + tj * 32 + tx];
        __syncthreads();
        #pragma unroll
        for (int p = 0; p < 4; ++p) {
            const int n = tj * 32 + ty + p * 8;      // output col
            const int k = ti * 32 + tx;              // input dim
            Wt[(size_t)(n >> 4) * 4096 + (k >> 5) * 512 + ((k >> 3) & 3) * 128
               + (n & 15) * 8 + (k & 7)] = f2bf(tilebuf[tx][ty + p * 8] * scale);
        }
    } else {
        const int tile = blk - 256;                  // 0..511 row-tiles of x
        const float* __restrict__ xs = x + (size_t)tile * 16 * EMB;
        ushort* __restrict__ xd = xb + (size_t)tile * 4096;
        #pragma unroll
        for (int j = 0; j < 16; ++j) {
            const int o = j * 256 + threadIdx.x;     // packed offset in tile
            const int ks = o >> 9, quad = (o >> 7) & 3, l16 = (o >> 3) & 15, e = o & 7;
            xd[o] = f2bf(xs[(size_t)l16 * EMB + ks * 32 + quad * 8 + e]);
        }
    }
}

// ---------------------------------------------------------------------------
// Kernel 1: QKV projection as MFMA GEMM (grid (128,3), acc[16]). A-frags
// from packed bf16 x (no cvt chain), B-frags from packed W — every load is
// base + lane*8 (1KB/wave coalesced). Outputs packed Q/K/V as in R8.
// ---------------------------------------------------------------------------
__global__ __launch_bounds__(256) void qkv_gemm(
    const ushort* __restrict__ xb,
    const ushort* __restrict__ Wqt, const ushort* __restrict__ Wkt,
    const ushort* __restrict__ Wvt,
    const float* __restrict__ bq, const float* __restrict__ bk,
    const float* __restrict__ bv,
    ushort* __restrict__ Qb, ushort* __restrict__ Kb, ushort* __restrict__ Vt)
{
    const int mat = blockIdx.y;
    const ushort* __restrict__ Wt = (mat == 0) ? Wqt : (mat == 1) ? Wkt : Wvt;
    const float* __restrict__ bias = (mat == 0) ? bq : (mat == 1) ? bk : bv;
    const float bscale = (mat == 0) ? QSCALE : 1.0f;

    const int w = threadIdx.x >> 6, lane = threadIdx.x & 63;
    const int quad = lane >> 4, l16 = lane & 15;
    const int row0 = blockIdx.x * 64 + w * 16;

    floatx4 acc[16];
    #pragma unroll
    for (int i = 0; i < 16; ++i) acc[i] = (floatx4){0.f, 0.f, 0.f, 0.f};

    const ushort* __restrict__ xrow = xb + (size_t)(blockIdx.x * 4 + w) * 4096 + lane * 8;
    const ushort* __restrict__ wrow = Wt + lane * 8;

    #pragma unroll
    for (int ks = 0; ks < 8; ++ks) {
        const short8 a = *(const short8*)(xrow + ks * 512);
        #pragma unroll
        for (int i = 0; i < 16; ++i) {
            const short8 bf = *(const short8*)(wrow + (size_t)i * 4096 + ks * 512);
            acc[i] = __builtin_amdgcn_mfma_f32_16x16x32_bf16(a, bf, acc[i], 0, 0, 0);
        }
    }

    const int gr0 = row0 + quad * 4;
    if (mat < 2) {
        ushort* __restrict__ dst = (mat == 0) ? Qb : Kb;
        #pragma unroll
        for (int i = 0; i < 16; ++i) {
            const int c = i * 16 + l16, h = c >> 5, d = c & (HD - 1);
            const float bb = bias[c] * bscale;
            #pragma unroll
            for (int r = 0; r < 4; ++r) {
                const int gr = gr0 + r, b = gr >> 10, n = gr & (SEQ - 1);
                // packed: [bh][n>>4][d>>3][n&15][d&7]
                dst[(size_t)(b * NH + h) * SEQ * HD + (size_t)(n >> 4) * 512
                    + (d >> 3) * 128 + (n & 15) * 8 + (d & 7)] = f2bf(acc[i][r] + bb);
            }
        }
    } else {
        const int b = gr0 >> 10, n0 = gr0 & (SEQ - 1);
        const int keyblk = n0 >> 5, j0 = n0 & 31;
        const int sg = (j0 & 15) >> 2, si0 = (j0 & 16) ? 4 : 0;
        #pragma unroll
        for (int i = 0; i < 16; ++i) {
            const int c = i * 16 + l16, h = c >> 5, d = c & (HD - 1);
            const float bb = bias[c];
            ushort4 t4;
            t4.x = f2bf(acc[i][0] + bb); t4.y = f2bf(acc[i][1] + bb);
            t4.z = f2bf(acc[i][2] + bb); t4.w = f2bf(acc[i][3] + bb);
            // packed: [bh][keyblk][d>>4][sg][d&15][si0..si0+3]
            *(ushort4*)(Vt + (size_t)(b * NH + h) * SEQ * HD + (size_t)keyblk * 1024
                        + (d >> 4) * 512 + sg * 128 + (d & 15) * 8 + si0) = t4;
        }
    }
}

// ---------------------------------------------------------------------------
// Kernel 2: attention, swapped-QK^T — R6/R8 structure FROZEN (512 thr, one
// head/wave, plain __syncthreads, depth-1 DMA dbuf; all schedule variants
// measured slower). Q/K/V from frag-packed layouts (R8). NEW: cp partials
// stored in packed [tile][h][l16][32] layout -> 1KB contiguous per wave
// (was 512B-strided, 8B/line).
// LDS 2*16*65*16 = 33280 B -> 4 blocks/CU.
// ---------------------------------------------------------------------------
__global__ __launch_bounds__(512) void attn_kernel(
    const ushort* __restrict__ Qb, const ushort* __restrict__ Kb,
    const ushort* __restrict__ Vt, const float* __restrict__ adj,
    const float* __restrict__ Wa, const float* __restrict__ ba,
    ushort* __restrict__ cp, float* __restrict__ lsum)
{
    __shared__ float4 Atile[2][16][65];      // +1 float4 row pad (DMA fills [0,64))
    const int tid = threadIdx.x, h = tid >> 6, lane = tid & 63;
    const int quad = lane >> 4, l16 = lane & 15;
    const int q0 = blockIdx.x * 16, b = blockIdx.y, z = blockIdx.z;
    const int bh = b * NH + h;
    const int kz = z * 512;

    const float LOG2E = 1.4426950408889634f;
    const float wa0 = Wa[0 * NH + h] * LOG2E, wa1 = Wa[1 * NH + h] * LOG2E;
    const float wa2 = Wa[2 * NH + h] * LOG2E, wa3 = Wa[3 * NH + h] * LOG2E;
    const float bah = ba[h] * LOG2E;

    // Q frag (B-operand of swapped QK), packed: one coalesced 1KB wave load
    const short8 aq = *(const short8*)(Qb + (size_t)bh * SEQ * HD
                                      + (size_t)blockIdx.x * 512 + lane * 8);

    floatx4 o0 = {0.f, 0.f, 0.f, 0.f}, o1 = {0.f, 0.f, 0.f, 0.f};
    float lacc = 0.f;

    const float4* __restrict__ adjb = (const float4*)adj + (size_t)b * SEQ * SEQ;
    // wave h DMAs adj rows 2h and 2h+1 of the block's 16-row tile
    const float4* __restrict__ asrc0 = adjb + (size_t)(q0 + 2 * h)     * SEQ + kz + lane;
    const float4* __restrict__ asrc1 = adjb + (size_t)(q0 + 2 * h + 1) * SEQ + kz + lane;

    const ushort* __restrict__ Kbase = Kb + (size_t)bh * SEQ * HD + lane * 8;
    const ushort* __restrict__ Vbase = Vt + (size_t)bh * SEQ * HD + lane * 8;

    // prologue: DMA tile 0
    gload_lds16(asrc0, &Atile[0][2 * h][0]);
    gload_lds16(asrc1, &Atile[0][2 * h + 1][0]);
    __syncthreads();   // implicit vmcnt(0) drain -> tile 0 resident

    for (int it = 0; it < 8; ++it) {          // 8 x 64 = 512 keys per split
        const int cur = it & 1;
        const int key0 = kz + it * 64;

        if (it < 7) {                          // async prefetch of next tile
            gload_lds16(asrc0 + (it + 1) * 64, &Atile[cur ^ 1][2 * h][0]);
            gload_lds16(asrc1 + (it + 1) * 64, &Atile[cur ^ 1][2 * h + 1][0]);
        }

        // K frags (A-operand), packed: 4 consecutive 1KB coalesced loads
        const ushort* kp = Kbase + (size_t)(key0 >> 4) * 512;
        const short8 k0 = *(const short8*)(kp);
        const short8 k1 = *(const short8*)(kp + 512);
        const short8 k2 = *(const short8*)(kp + 1024);
        const short8 k3 = *(const short8*)(kp + 1536);
        const floatx4 zz = {0.f, 0.f, 0.f, 0.f};
        floatx4 s0 = __builtin_amdgcn_mfma_f32_16x16x32_bf16(k0, aq, zz, 0, 0, 0);
        floatx4 s1 = __builtin_amdgcn_mfma_f32_16x16x32_bf16(k1, aq, zz, 0, 0, 0);
        floatx4 s2 = __builtin_amdgcn_mfma_f32_16x16x32_bf16(k2, aq, zz, 0, 0, 0);
        floatx4 s3 = __builtin_amdgcn_mfma_f32_16x16x32_bf16(k3, aq, zz, 0, 0, 0);

        // bias + exp2; lane covers q = l16, keys = 16t + 4*quad + r.
        ushort pu0[8], pu1[8];
        #pragma unroll
        for (int r = 0; r < 4; ++r) {
            const int col = 4 * quad + r;
            const float4 a0 = Atile[cur][l16][col];
            const float4 a1 = Atile[cur][l16][16 + col];
            const float4 a2 = Atile[cur][l16][32 + col];
            const float4 a3 = Atile[cur][l16][48 + col];
            const float b0 = fmaf(a0.x, wa0, fmaf(a0.y, wa1, fmaf(a0.z, wa2, fmaf(a0.w, wa3, bah))));
            const float b1 = fmaf(a1.x, wa0, fmaf(a1.y, wa1, fmaf(a1.z, wa2, fmaf(a1.w, wa3, bah))));
            const float b2 = fmaf(a2.x, wa0, fmaf(a2.y, wa1, fmaf(a2.z, wa2, fmaf(a2.w, wa3, bah))));
            const float b3 = fmaf(a3.x, wa0, fmaf(a3.y, wa1, fmaf(a3.z, wa2, fmaf(a3.w, wa3, bah))));
            const float p0 = __builtin_amdgcn_exp2f(s0[r] + b0);
            const float p1 = __builtin_amdgcn_exp2f(s1[r] + b1);
            const float p2 = __builtin_amdgcn_exp2f(s2[r] + b2);
            const float p3 = __builtin_amdgcn_exp2f(s3[r] + b3);
            lacc += (p0 + p1) + (p2 + p3);
            pu0[r]     = f2bf(p0);   // k-slot 8*quad+r     -> key 16*0+4q+r
            pu0[4 + r] = f2bf(p1);   // k-slot 8*quad+4+r   -> key 16*1+4q+r
            pu1[r]     = f2bf(p2);   // same, keys +32
            pu1[4 + r] = f2bf(p3);   // same, keys +48
        }
        const short8 pf0 = *(const short8*)pu0;
        const short8 pf1 = *(const short8*)pu1;

        // V frags (A-operand), packed: 4 consecutive 1KB coalesced loads
        const ushort* vp = Vbase + (size_t)(key0 >> 5) * 1024;
        const short8 v00 = *(const short8*)(vp);          // d=l16,    keys blk0
        const short8 v10 = *(const short8*)(vp + 512);    // d=16+l16, keys blk0
        const short8 v01 = *(const short8*)(vp + 1024);   // d=l16,    keys blk1
        const short8 v11 = *(const short8*)(vp + 1536);   // d=16+l16, keys blk1
        o0 = __builtin_amdgcn_mfma_f32_16x16x32_bf16(v00, pf0, o0, 0, 0, 0);
        o1 = __builtin_amdgcn_mfma_f32_16x16x32_bf16(v10, pf0, o1, 0, 0, 0);
        o0 = __builtin_amdgcn_mfma_f32_16x16x32_bf16(v01, pf1, o0, 0, 0, 0);
        o1 = __builtin_amdgcn_mfma_f32_16x16x32_bf16(v11, pf1, o1, 0, 0, 0);

        __syncthreads();   // all waves done with Atile[cur]; next DMA arrived
    }

    // key dim is lane-local; only the quad (key-block) reduction remains
    lacc += __shfl_xor(lacc, 16, 64);
    lacc += __shfl_xor(lacc, 32, 64);

    ushort* __restrict__ cpz = cp + (size_t)z * BATCH * SEQ * EMB;
    float* __restrict__ lsz = lsum + (size_t)z * BATCH * SEQ * NH;
    // packed cp: [tile][h][l16][d%32]; lane holds d = 4*quad + r (+16), q=l16
    const size_t tbase = ((size_t)b * 64 + blockIdx.x) * 4096 + (size_t)h * 512
                       + l16 * 32 + 4 * quad;
    ushort4 t0, t1;
    t0.x = f2bf(o0[0]); t0.y = f2bf(o0[1]); t0.z = f2bf(o0[2]); t0.w = f2bf(o0[3]);
    t1.x = f2bf(o1[0]); t1.y = f2bf(o1[1]); t1.z = f2bf(o1[2]); t1.w = f2bf(o1[3]);
    *(ushort4*)(cpz + tbase)      = t0;
    *(ushort4*)(cpz + tbase + 16) = t1;
    const size_t grow = (size_t)b * SEQ + q0 + l16;
    if (quad == 0) lsz[grow * NH + h] = lacc;
}

// ---------------------------------------------------------------------------
// Kernel 3: outproj as MFMA GEMM. A-frags from packed cp (1KB/wave), B-frags
// from packed Wot (lane*8). Combines the two bf16 key-split partials (fp32
// add), normalizes by l, epilogue + bo + x residual. Grid (128,2).
// ---------------------------------------------------------------------------
__global__ __launch_bounds__(256) void outproj_gemm(
    const ushort* __restrict__ cp, const float* __restrict__ lsum,
    const ushort* __restrict__ Wot, const float* __restrict__ bo,
    const float* __restrict__ x, float* __restrict__ out)
{
    const int w = threadIdx.x >> 6, lane = threadIdx.x & 63;
    const int quad = lane >> 4, l16 = lane & 15;
    const int row0 = blockIdx.x * 64 + w * 16;
    const int c0 = blockIdx.y * 128;     // column half
    const int arow = row0 + l16;
    const ushort* __restrict__ cp1 = cp + (size_t)BATCH * SEQ * EMB;
    const float* __restrict__ l1  = lsum + (size_t)BATCH * SEQ * NH;

    // packed cp row base for this wave's 16-row tile
    const size_t tb = (size_t)(blockIdx.x * 4 + w) * 4096 + l16 * 32 + quad * 8;
    const ushort* __restrict__ wrow = Wot + (size_t)(c0 >> 4) * 4096 + lane * 8;

    floatx4 acc[8];
    #pragma unroll
    for (int i = 0; i < 8; ++i) acc[i] = (floatx4){0.f, 0.f, 0.f, 0.f};

    #pragma unroll
    for (int ks = 0; ks < 8; ++ks) {
        const float invl = 1.0f / (lsum[(size_t)arow * NH + ks] + l1[(size_t)arow * NH + ks]);
        const ushort4 c00 = *(const ushort4*)(cp  + tb + ks * 512);
        const ushort4 c01 = *(const ushort4*)(cp  + tb + ks * 512 + 4);
        const ushort4 c10 = *(const ushort4*)(cp1 + tb + ks * 512);
        const ushort4 c11 = *(const ushort4*)(cp1 + tb + ks * 512 + 4);
        ushort au[8] = {
            f2bf((bf2f(c00.x) + bf2f(c10.x)) * invl),
            f2bf((bf2f(c00.y) + bf2f(c10.y)) * invl),
            f2bf((bf2f(c00.z) + bf2f(c10.z)) * invl),
            f2bf((bf2f(c00.w) + bf2f(c10.w)) * invl),
            f2bf((bf2f(c01.x) + bf2f(c11.x)) * invl),
            f2bf((bf2f(c01.y) + bf2f(c11.y)) * invl),
            f2bf((bf2f(c01.z) + bf2f(c11.z)) * invl),
            f2bf((bf2f(c01.w) + bf2f(c11.w)) * invl)};
        const short8 a = *(const short8*)au;
        #pragma unroll
        for (int i = 0; i < 8; ++i) {
            const short8 bfr = *(const short8*)(wrow + (size_t)i * 4096 + ks * 512);
            acc[i] = __builtin_amdgcn_mfma_f32_16x16x32_bf16(a, bfr, acc[i], 0, 0, 0);
        }
    }

    const int gr0 = row0 + quad * 4;
    #pragma unroll
    for (int i = 0; i < 8; ++i) {
        const int c = c0 + i * 16 + l16;
        const float bov = bo[c];
        #pragma unroll
        for (int r = 0; r < 4; ++r) {
            const size_t idx = (size_t)(gr0 + r) * EMB + c;
            out[idx] = acc[i][r] + bov + x[idx];
        }
    }
}

extern "C" void kernel_launch(void* const* d_in, const int* in_sizes, int n_in,
                              void* d_out, int out_size, void* d_ws, size_t ws_size,
                              hipStream_t stream) {
    const float* x   = (const float*)d_in[0];
    const float* adj = (const float*)d_in[1];
    const float* Wq  = (const float*)d_in[2];
    const float* bq  = (const float*)d_in[3];
    const float* Wk  = (const float*)d_in[4];
    const float* bk  = (const float*)d_in[5];
    const float* Wv  = (const float*)d_in[6];
    const float* bv  = (const float*)d_in[7];
    const float* Wo  = (const float*)d_in[8];
    const float* bo  = (const float*)d_in[9];
    const float* Wa  = (const float*)d_in[10];
    const float* ba  = (const float*)d_in[11];

    const size_t per = (size_t)BATCH * NH * SEQ * HD;   // 2,097,152
    ushort* Qb  = (ushort*)d_ws;
    ushort* Kb  = Qb + per;
    ushort* Vt  = Kb + per;
    ushort* Wqt = Vt + per;
    ushort* Wkt = Wqt + EMB * EMB;
    ushort* Wvt = Wkt + EMB * EMB;
    ushort* Wot = Wvt + EMB * EMB;
    ushort* cpw = Wot + EMB * EMB;                      // 2 x 4 MB bf16
    ushort* xbp = cpw + 2 * (size_t)BATCH * SEQ * EMB;  // 4 MB bf16 packed x
    float*  ls  = (float*)(xbp + (size_t)BATCH * SEQ * EMB);  // 2 x 256 KB

    prep_kernel<<<768, 256, 0, stream>>>(Wq, Wk, Wv, Wo, x,
                                         Wqt, Wkt, Wvt, Wot, xbp);
    qkv_gemm<<<dim3(BATCH * SEQ / 64, 3), 256, 0, stream>>>(
        xbp, Wqt, Wkt, Wvt, bq, bk, bv, Qb, Kb, Vt);
    attn_kernel<<<dim3(SEQ / 16, BATCH, 2), 512, 0, stream>>>(
        Qb, Kb, Vt, adj, Wa, ba, cpw, ls);
    outproj_gemm<<<dim3(BATCH * SEQ / 64, 2), 256, 0, stream>>>(
        cpw, ls, Wot, bo, x, (float*)d_out);
}

// Round 10
// 265.616 us; speedup vs baseline: 1.1587x; 1.0391x over previous
//
#include <hip/hip_runtime.h>
#include <hip/hip_bf16.h>

// GraphTransformerLayer: B=8, N=1024, E=256, H=8, D=32, C=4 (all fp32 in/out)
#define BATCH 8
#define SEQ   1024
#define EMB   256
#define NH    8
#define HD    32
#define QSCALE 0.2550030053f   // log2(e)/sqrt(32), folded into Wq/bq

typedef __attribute__((ext_vector_type(8))) short short8;
typedef __attribute__((ext_vector_type(4))) float floatx4;

__device__ __forceinline__ ushort f2bf(float f) {
    __hip_bfloat16 h = __float2bfloat16(f);
    return *reinterpret_cast<ushort*>(&h);
}

__device__ __forceinline__ float bf2f(ushort u) {
    unsigned v = ((unsigned)u) << 16;
    return __builtin_bit_cast(float, v);
}

// async 16B/lane global->LDS DMA: each lane loads 16B from its own global
// address into wave-uniform LDS base + lane*16 (m97/m104 semantics).
__device__ __forceinline__ void gload_lds16(const float4* g, float4* l) {
    __builtin_amdgcn_global_load_lds(
        (const __attribute__((address_space(1))) unsigned int*)g,
        (__attribute__((address_space(3))) unsigned int*)l, 16, 0, 0);
}

// ---------------------------------------------------------------------------
// Frag-packed layouts (R8/R9: 16-lines-per-instruction address divergence was
// the invisible TA bottleneck; every GEMM operand loads base + lane*8):
//   W (all 4):  [c/16][ks][quad][l16][8]
//   x packed:   [n/16][ks][quad][l16][8]
//   Q,K:        [bh][n/16][d/8][n%16][d%8]
//   V:          [bh][key/32][d/16][sg][d%16][si]  (quad-interleaved slots)
//   cp:         [tile=n/16][h][l16=n%16][d%32]
// ---------------------------------------------------------------------------

// Kernel 0: prep. blocks 0..255: transpose+pack Wq,Wk,Wv,Wo (Wq pre-scaled
// by log2(e)/sqrt(32)). blocks 256..767: pack x -> bf16 frag layout.
__global__ __launch_bounds__(256) void prep_kernel(
    const float* __restrict__ Wq, const float* __restrict__ Wk,
    const float* __restrict__ Wv, const float* __restrict__ Wo,
    const float* __restrict__ x,
    ushort* __restrict__ Wqt, ushort* __restrict__ Wkt,
    ushort* __restrict__ Wvt, ushort* __restrict__ Wot,
    ushort* __restrict__ xb)
{
    const int blk = blockIdx.x;
    if (blk < 256) {
        __shared__ float tilebuf[32][33];
        const int mat = blk >> 6, tile = blk & 63;
        const int ti = tile >> 3, tj = tile & 7;     // ti: k-tile, tj: n-tile
        const float* W = (mat == 0) ? Wq : (mat == 1) ? Wk : (mat == 2) ? Wv : Wo;
        ushort* Wt = (mat == 0) ? Wqt : (mat == 1) ? Wkt : (mat == 2) ? Wvt : Wot;
        const float scale = (mat == 0) ? QSCALE : 1.0f;

        const int tx = threadIdx.x & 31, ty = threadIdx.x >> 5;  // 32 x 8
        #pragma unroll
        for (int p = 0; p < 4; ++p)
            tilebuf[ty + p * 8][tx] = W[(size_t)(ti * 32 + ty + p * 8) * EMB + tj * 32 + tx];
        __syncthreads();
        #pragma unroll
        for (int p = 0; p < 4; ++p) {
            const int n = tj * 32 + ty + p * 8;      // output col
            const int k = ti * 32 + tx;              // input dim
            Wt[(size_t)(n >> 4) * 4096 + (k >> 5) * 512 + ((k >> 3) & 3) * 128
               + (n & 15) * 8 + (k & 7)] = f2bf(tilebuf[tx][ty + p * 8] * scale);
        }
    } else {
        const int tile = blk - 256;                  // 0..511 row-tiles of x
        const float* __restrict__ xs = x + (size_t)tile * 16 * EMB;
        ushort* __restrict__ xd = xb + (size_t)tile * 4096;
        #pragma unroll
        for (int j = 0; j < 16; ++j) {
            const int o = j * 256 + threadIdx.x;     // packed offset in tile
            const int ks = o >> 9, quad = (o >> 7) & 3, l16 = (o >> 3) & 15, e = o & 7;
            xd[o] = f2bf(xs[(size_t)l16 * EMB + ks * 32 + quad * 8 + e]);
        }
    }
}

// ---------------------------------------------------------------------------
// Kernel 1: QKV projection as MFMA GEMM (grid (128,3), acc[16]). A-frags
// from packed bf16 x, B-frags from packed W — every load base + lane*8.
// Outputs packed Q/K/V.
// ---------------------------------------------------------------------------
__global__ __launch_bounds__(256) void qkv_gemm(
    const ushort* __restrict__ xb,
    const ushort* __restrict__ Wqt, const ushort* __restrict__ Wkt,
    const ushort* __restrict__ Wvt,
    const float* __restrict__ bq, const float* __restrict__ bk,
    const float* __restrict__ bv,
    ushort* __restrict__ Qb, ushort* __restrict__ Kb, ushort* __restrict__ Vt)
{
    const int mat = blockIdx.y;
    const ushort* __restrict__ Wt = (mat == 0) ? Wqt : (mat == 1) ? Wkt : Wvt;
    const float* __restrict__ bias = (mat == 0) ? bq : (mat == 1) ? bk : bv;
    const float bscale = (mat == 0) ? QSCALE : 1.0f;

    const int w = threadIdx.x >> 6, lane = threadIdx.x & 63;
    const int quad = lane >> 4, l16 = lane & 15;
    const int row0 = blockIdx.x * 64 + w * 16;

    floatx4 acc[16];
    #pragma unroll
    for (int i = 0; i < 16; ++i) acc[i] = (floatx4){0.f, 0.f, 0.f, 0.f};

    const ushort* __restrict__ xrow = xb + (size_t)(blockIdx.x * 4 + w) * 4096 + lane * 8;
    const ushort* __restrict__ wrow = Wt + lane * 8;

    #pragma unroll
    for (int ks = 0; ks < 8; ++ks) {
        const short8 a = *(const short8*)(xrow + ks * 512);
        #pragma unroll
        for (int i = 0; i < 16; ++i) {
            const short8 bf = *(const short8*)(wrow + (size_t)i * 4096 + ks * 512);
            acc[i] = __builtin_amdgcn_mfma_f32_16x16x32_bf16(a, bf, acc[i], 0, 0, 0);
        }
    }

    const int gr0 = row0 + quad * 4;
    if (mat < 2) {
        ushort* __restrict__ dst = (mat == 0) ? Qb : Kb;
        #pragma unroll
        for (int i = 0; i < 16; ++i) {
            const int c = i * 16 + l16, h = c >> 5, d = c & (HD - 1);
            const float bb = bias[c] * bscale;
            #pragma unroll
            for (int r = 0; r < 4; ++r) {
                const int gr = gr0 + r, b = gr >> 10, n = gr & (SEQ - 1);
                // packed: [bh][n>>4][d>>3][n&15][d&7]
                dst[(size_t)(b * NH + h) * SEQ * HD + (size_t)(n >> 4) * 512
                    + (d >> 3) * 128 + (n & 15) * 8 + (d & 7)] = f2bf(acc[i][r] + bb);
            }
        }
    } else {
        const int b = gr0 >> 10, n0 = gr0 & (SEQ - 1);
        const int keyblk = n0 >> 5, j0 = n0 & 31;
        const int sg = (j0 & 15) >> 2, si0 = (j0 & 16) ? 4 : 0;
        #pragma unroll
        for (int i = 0; i < 16; ++i) {
            const int c = i * 16 + l16, h = c >> 5, d = c & (HD - 1);
            const float bb = bias[c];
            ushort4 t4;
            t4.x = f2bf(acc[i][0] + bb); t4.y = f2bf(acc[i][1] + bb);
            t4.z = f2bf(acc[i][2] + bb); t4.w = f2bf(acc[i][3] + bb);
            // packed: [bh][keyblk][d>>4][sg][d&15][si0..si0+3]
            *(ushort4*)(Vt + (size_t)(b * NH + h) * SEQ * HD + (size_t)keyblk * 1024
                        + (d >> 4) * 512 + sg * 128 + (d & 15) * 8 + si0) = t4;
        }
    }
}

// ---------------------------------------------------------------------------
// Kernel 2: attention, swapped-QK^T — QBLK=32: each wave computes one head x
// 32 q-rows (two 16-row fragments A/B sharing the SAME K/V frag loads).
// R9 accounting: K/V loads depend only on (head, keyblock), so doubling
// q-rows per block halves TA instructions (the proven bottleneck) and
// barrier rendezvous per unit work. Frozen R1 schedule otherwise: plain
// __syncthreads, depth-1 DMA dbuf, zero inline asm. K frags freed before V
// frags load to bound VGPR (<128, enforced by launch_bounds(512,4)).
// LDS 2*32*65*16 = 66560 B -> 2 blocks/CU, 16 waves/CU.
// ---------------------------------------------------------------------------
__global__ __launch_bounds__(512, 4) void attn_kernel(
    const ushort* __restrict__ Qb, const ushort* __restrict__ Kb,
    const ushort* __restrict__ Vt, const float* __restrict__ adj,
    const float* __restrict__ Wa, const float* __restrict__ ba,
    ushort* __restrict__ cp, float* __restrict__ lsum)
{
    __shared__ float4 Atile[2][32][65];      // +1 float4 row pad (DMA fills [0,64))
    const int tid = threadIdx.x, h = tid >> 6, lane = tid & 63;
    const int quad = lane >> 4, l16 = lane & 15;
    const int q0 = blockIdx.x * 32, b = blockIdx.y, z = blockIdx.z;
    const int bh = b * NH + h;
    const int kz = z * 512;

    const float LOG2E = 1.4426950408889634f;
    const float wa0 = Wa[0 * NH + h] * LOG2E, wa1 = Wa[1 * NH + h] * LOG2E;
    const float wa2 = Wa[2 * NH + h] * LOG2E, wa3 = Wa[3 * NH + h] * LOG2E;
    const float bah = ba[h] * LOG2E;

    // Q frags (B-operand of swapped QK), packed: two coalesced 1KB wave loads
    const ushort* __restrict__ qbase = Qb + (size_t)bh * SEQ * HD + lane * 8;
    const short8 aqA = *(const short8*)(qbase + (size_t)(blockIdx.x * 2)     * 512);
    const short8 aqB = *(const short8*)(qbase + (size_t)(blockIdx.x * 2 + 1) * 512);

    floatx4 oA0 = {0.f, 0.f, 0.f, 0.f}, oA1 = {0.f, 0.f, 0.f, 0.f};
    floatx4 oB0 = {0.f, 0.f, 0.f, 0.f}, oB1 = {0.f, 0.f, 0.f, 0.f};
    float laccA = 0.f, laccB = 0.f;

    const float4* __restrict__ adjb = (const float4*)adj + (size_t)b * SEQ * SEQ;
    // wave h DMAs adj rows 4h..4h+3 of the block's 32-row tile
    const float4* asrc[4];
    #pragma unroll
    for (int p = 0; p < 4; ++p)
        asrc[p] = adjb + (size_t)(q0 + 4 * h + p) * SEQ + kz + lane;

    const ushort* __restrict__ Kbase = Kb + (size_t)bh * SEQ * HD + lane * 8;
    const ushort* __restrict__ Vbase = Vt + (size_t)bh * SEQ * HD + lane * 8;

    // prologue: DMA tile 0
    #pragma unroll
    for (int p = 0; p < 4; ++p)
        gload_lds16(asrc[p], &Atile[0][4 * h + p][0]);
    __syncthreads();   // implicit vmcnt(0) drain -> tile 0 resident

    for (int it = 0; it < 8; ++it) {          // 8 x 64 = 512 keys per split
        const int cur = it & 1;
        const int key0 = kz + it * 64;

        if (it < 7) {                          // async prefetch of next tile
            #pragma unroll
            for (int p = 0; p < 4; ++p)
                gload_lds16(asrc[p] + (it + 1) * 64, &Atile[cur ^ 1][4 * h + p][0]);
        }

        // K frags (A-operand), packed, SHARED by both q-fragments
        const ushort* kp = Kbase + (size_t)(key0 >> 4) * 512;
        const short8 k0 = *(const short8*)(kp);
        const short8 k1 = *(const short8*)(kp + 512);
        const short8 k2 = *(const short8*)(kp + 1024);
        const short8 k3 = *(const short8*)(kp + 1536);
        const floatx4 zz = {0.f, 0.f, 0.f, 0.f};
        floatx4 sA0 = __builtin_amdgcn_mfma_f32_16x16x32_bf16(k0, aqA, zz, 0, 0, 0);
        floatx4 sA1 = __builtin_amdgcn_mfma_f32_16x16x32_bf16(k1, aqA, zz, 0, 0, 0);
        floatx4 sA2 = __builtin_amdgcn_mfma_f32_16x16x32_bf16(k2, aqA, zz, 0, 0, 0);
        floatx4 sA3 = __builtin_amdgcn_mfma_f32_16x16x32_bf16(k3, aqA, zz, 0, 0, 0);
        floatx4 sB0 = __builtin_amdgcn_mfma_f32_16x16x32_bf16(k0, aqB, zz, 0, 0, 0);
        floatx4 sB1 = __builtin_amdgcn_mfma_f32_16x16x32_bf16(k1, aqB, zz, 0, 0, 0);
        floatx4 sB2 = __builtin_amdgcn_mfma_f32_16x16x32_bf16(k2, aqB, zz, 0, 0, 0);
        floatx4 sB3 = __builtin_amdgcn_mfma_f32_16x16x32_bf16(k3, aqB, zz, 0, 0, 0);

        // bias + exp2; lane covers q = l16 (frag A) / 16+l16 (frag B),
        // keys = 16t + 4*quad + r.
        ushort puA0[8], puA1[8], puB0[8], puB1[8];
        #pragma unroll
        for (int r = 0; r < 4; ++r) {
            const int col = 4 * quad + r;
            // frag A: rows l16
            {
                const float4 a0 = Atile[cur][l16][col];
                const float4 a1 = Atile[cur][l16][16 + col];
                const float4 a2 = Atile[cur][l16][32 + col];
                const float4 a3 = Atile[cur][l16][48 + col];
                const float b0 = fmaf(a0.x, wa0, fmaf(a0.y, wa1, fmaf(a0.z, wa2, fmaf(a0.w, wa3, bah))));
                const float b1 = fmaf(a1.x, wa0, fmaf(a1.y, wa1, fmaf(a1.z, wa2, fmaf(a1.w, wa3, bah))));
                const float b2 = fmaf(a2.x, wa0, fmaf(a2.y, wa1, fmaf(a2.z, wa2, fmaf(a2.w, wa3, bah))));
                const float b3 = fmaf(a3.x, wa0, fmaf(a3.y, wa1, fmaf(a3.z, wa2, fmaf(a3.w, wa3, bah))));
                const float p0 = __builtin_amdgcn_exp2f(sA0[r] + b0);
                const float p1 = __builtin_amdgcn_exp2f(sA1[r] + b1);
                const float p2 = __builtin_amdgcn_exp2f(sA2[r] + b2);
                const float p3 = __builtin_amdgcn_exp2f(sA3[r] + b3);
                laccA += (p0 + p1) + (p2 + p3);
                puA0[r] = f2bf(p0); puA0[4 + r] = f2bf(p1);
                puA1[r] = f2bf(p2); puA1[4 + r] = f2bf(p3);
            }
            // frag B: rows 16+l16
            {
                const float4 a0 = Atile[cur][16 + l16][col];
                const float4 a1 = Atile[cur][16 + l16][16 + col];
                const float4 a2 = Atile[cur][16 + l16][32 + col];
                const float4 a3 = Atile[cur][16 + l16][48 + col];
                const float b0 = fmaf(a0.x, wa0, fmaf(a0.y, wa1, fmaf(a0.z, wa2, fmaf(a0.w, wa3, bah))));
                const float b1 = fmaf(a1.x, wa0, fmaf(a1.y, wa1, fmaf(a1.z, wa2, fmaf(a1.w, wa3, bah))));
                const float b2 = fmaf(a2.x, wa0, fmaf(a2.y, wa1, fmaf(a2.z, wa2, fmaf(a2.w, wa3, bah))));
                const float b3 = fmaf(a3.x, wa0, fmaf(a3.y, wa1, fmaf(a3.z, wa2, fmaf(a3.w, wa3, bah))));
                const float p0 = __builtin_amdgcn_exp2f(sB0[r] + b0);
                const float p1 = __builtin_amdgcn_exp2f(sB1[r] + b1);
                const float p2 = __builtin_amdgcn_exp2f(sB2[r] + b2);
                const float p3 = __builtin_amdgcn_exp2f(sB3[r] + b3);
                laccB += (p0 + p1) + (p2 + p3);
                puB0[r] = f2bf(p0); puB0[4 + r] = f2bf(p1);
                puB1[r] = f2bf(p2); puB1[4 + r] = f2bf(p3);
            }
        }
        const short8 pfA0 = *(const short8*)puA0;
        const short8 pfA1 = *(const short8*)puA1;
        const short8 pfB0 = *(const short8*)puB0;
        const short8 pfB1 = *(const short8*)puB1;

        // V frags (A-operand), packed, SHARED by both q-fragments
        const ushort* vp = Vbase + (size_t)(key0 >> 5) * 1024;
        const short8 v00 = *(const short8*)(vp);          // d=l16,    keys blk0
        const short8 v10 = *(const short8*)(vp + 512);    // d=16+l16, keys blk0
        const short8 v01 = *(const short8*)(vp + 1024);   // d=l16,    keys blk1
        const short8 v11 = *(const short8*)(vp + 1536);   // d=16+l16, keys blk1
        oA0 = __builtin_amdgcn_mfma_f32_16x16x32_bf16(v00, pfA0, oA0, 0, 0, 0);
        oA1 = __builtin_amdgcn_mfma_f32_16x16x32_bf16(v10, pfA0, oA1, 0, 0, 0);
        oA0 = __builtin_amdgcn_mfma_f32_16x16x32_bf16(v01, pfA1, oA0, 0, 0, 0);
        oA1 = __builtin_amdgcn_mfma_f32_16x16x32_bf16(v11, pfA1, oA1, 0, 0, 0);
        oB0 = __builtin_amdgcn_mfma_f32_16x16x32_bf16(v00, pfB0, oB0, 0, 0, 0);
        oB1 = __builtin_amdgcn_mfma_f32_16x16x32_bf16(v10, pfB0, oB1, 0, 0, 0);
        oB0 = __builtin_amdgcn_mfma_f32_16x16x32_bf16(v01, pfB1, oB0, 0, 0, 0);
        oB1 = __builtin_amdgcn_mfma_f32_16x16x32_bf16(v11, pfB1, oB1, 0, 0, 0);

        __syncthreads();   // all waves done with Atile[cur]; next DMA arrived
    }

    // key dim is lane-local; only the quad (key-block) reduction remains
    laccA += __shfl_xor(laccA, 16, 64);
    laccA += __shfl_xor(laccA, 32, 64);
    laccB += __shfl_xor(laccB, 16, 64);
    laccB += __shfl_xor(laccB, 32, 64);

    ushort* __restrict__ cpz = cp + (size_t)z * BATCH * SEQ * EMB;
    float* __restrict__ lsz = lsum + (size_t)z * BATCH * SEQ * NH;
    // packed cp: [tile][h][l16][d%32]; lane holds d = 4*quad + r (+16)
    const size_t tA = ((size_t)b * 64 + blockIdx.x * 2)     * 4096 + (size_t)h * 512
                    + l16 * 32 + 4 * quad;
    const size_t tB = ((size_t)b * 64 + blockIdx.x * 2 + 1) * 4096 + (size_t)h * 512
                    + l16 * 32 + 4 * quad;
    ushort4 t;
    t.x = f2bf(oA0[0]); t.y = f2bf(oA0[1]); t.z = f2bf(oA0[2]); t.w = f2bf(oA0[3]);
    *(ushort4*)(cpz + tA)      = t;
    t.x = f2bf(oA1[0]); t.y = f2bf(oA1[1]); t.z = f2bf(oA1[2]); t.w = f2bf(oA1[3]);
    *(ushort4*)(cpz + tA + 16) = t;
    t.x = f2bf(oB0[0]); t.y = f2bf(oB0[1]); t.z = f2bf(oB0[2]); t.w = f2bf(oB0[3]);
    *(ushort4*)(cpz + tB)      = t;
    t.x = f2bf(oB1[0]); t.y = f2bf(oB1[1]); t.z = f2bf(oB1[2]); t.w = f2bf(oB1[3]);
    *(ushort4*)(cpz + tB + 16) = t;
    if (quad == 0) {
        const size_t growA = (size_t)b * SEQ + q0 + l16;
        lsz[growA * NH + h]        = laccA;
        lsz[(growA + 16) * NH + h] = laccB;
    }
}

// ---------------------------------------------------------------------------
// Kernel 3: outproj as MFMA GEMM. A-frags from packed cp (1KB/wave), B-frags
// from packed Wot (lane*8). Combines the two bf16 key-split partials (fp32
// add), normalizes by l, epilogue + bo + x residual. Grid (128,2).
// ---------------------------------------------------------------------------
__global__ __launch_bounds__(256) void outproj_gemm(
    const ushort* __restrict__ cp, const float* __restrict__ lsum,
    const ushort* __restrict__ Wot, const float* __restrict__ bo,
    const float* __restrict__ x, float* __restrict__ out)
{
    const int w = threadIdx.x >> 6, lane = threadIdx.x & 63;
    const int quad = lane >> 4, l16 = lane & 15;
    const int row0 = blockIdx.x * 64 + w * 16;
    const int c0 = blockIdx.y * 128;     // column half
    const int arow = row0 + l16;
    const ushort* __restrict__ cp1 = cp + (size_t)BATCH * SEQ * EMB;
    const float* __restrict__ l1  = lsum + (size_t)BATCH * SEQ * NH;

    // packed cp row base for this wave's 16-row tile
    const size_t tb = (size_t)(blockIdx.x * 4 + w) * 4096 + l16 * 32 + quad * 8;
    const ushort* __restrict__ wrow = Wot + (size_t)(c0 >> 4) * 4096 + lane * 8;

    floatx4 acc[8];
    #pragma unroll
    for (int i = 0; i < 8; ++i) acc[i] = (floatx4){0.f, 0.f, 0.f, 0.f};

    #pragma unroll
    for (int ks = 0; ks < 8; ++ks) {
        const float invl = 1.0f / (lsum[(size_t)arow * NH + ks] + l1[(size_t)arow * NH + ks]);
        const ushort4 c00 = *(const ushort4*)(cp  + tb + ks * 512);
        const ushort4 c01 = *(const ushort4*)(cp  + tb + ks * 512 + 4);
        const ushort4 c10 = *(const ushort4*)(cp1 + tb + ks * 512);
        const ushort4 c11 = *(const ushort4*)(cp1 + tb + ks * 512 + 4);
        ushort au[8] = {
            f2bf((bf2f(c00.x) + bf2f(c10.x)) * invl),
            f2bf((bf2f(c00.y) + bf2f(c10.y)) * invl),
            f2bf((bf2f(c00.z) + bf2f(c10.z)) * invl),
            f2bf((bf2f(c00.w) + bf2f(c10.w)) * invl),
            f2bf((bf2f(c01.x) + bf2f(c11.x)) * invl),
            f2bf((bf2f(c01.y) + bf2f(c11.y)) * invl),
            f2bf((bf2f(c01.z) + bf2f(c11.z)) * invl),
            f2bf((bf2f(c01.w) + bf2f(c11.w)) * invl)};
        const short8 a = *(const short8*)au;
        #pragma unroll
        for (int i = 0; i < 8; ++i) {
            const short8 bfr = *(const short8*)(wrow + (size_t)i * 4096 + ks * 512);
            acc[i] = __builtin_amdgcn_mfma_f32_16x16x32_bf16(a, bfr, acc[i], 0, 0, 0);
        }
    }

    const int gr0 = row0 + quad * 4;
    #pragma unroll
    for (int i = 0; i < 8; ++i) {
        const int c = c0 + i * 16 + l16;
        const float bov = bo[c];
        #pragma unroll
        for (int r = 0; r < 4; ++r) {
            const size_t idx = (size_t)(gr0 + r) * EMB + c;
            out[idx] = acc[i][r] + bov + x[idx];
        }
    }
}

extern "C" void kernel_launch(void* const* d_in, const int* in_sizes, int n_in,
                              void* d_out, int out_size, void* d_ws, size_t ws_size,
                              hipStream_t stream) {
    const float* x   = (const float*)d_in[0];
    const float* adj = (const float*)d_in[1];
    const float* Wq  = (const float*)d_in[2];
    const float* bq  = (const float*)d_in[3];
    const float* Wk  = (const float*)d_in[4];
    const float* bk  = (const float*)d_in[5];
    const float* Wv  = (const float*)d_in[6];
    const float* bv  = (const float*)d_in[7];
    const float* Wo  = (const float*)d_in[8];
    const float* bo  = (const float*)d_in[9];
    const float* Wa  = (const float*)d_in[10];
    const float* ba  = (const float*)d_in[11];

    const size_t per = (size_t)BATCH * NH * SEQ * HD;   // 2,097,152
    ushort* Qb  = (ushort*)d_ws;
    ushort* Kb  = Qb + per;
    ushort* Vt  = Kb + per;
    ushort* Wqt = Vt + per;
    ushort* Wkt = Wqt + EMB * EMB;
    ushort* Wvt = Wkt + EMB * EMB;
    ushort* Wot = Wvt + EMB * EMB;
    ushort* cpw = Wot + EMB * EMB;                      // 2 x 4 MB bf16
    ushort* xbp = cpw + 2 * (size_t)BATCH * SEQ * EMB;  // 4 MB bf16 packed x
    float*  ls  = (float*)(xbp + (size_t)BATCH * SEQ * EMB);  // 2 x 256 KB

    prep_kernel<<<768, 256, 0, stream>>>(Wq, Wk, Wv, Wo, x,
                                         Wqt, Wkt, Wvt, Wot, xbp);
    qkv_gemm<<<dim3(BATCH * SEQ / 64, 3), 256, 0, stream>>>(
        xbp, Wqt, Wkt, Wvt, bq, bk, bv, Qb, Kb, Vt);
    attn_kernel<<<dim3(SEQ / 32, BATCH, 2), 512, 0, stream>>>(
        Qb, Kb, Vt, adj, Wa, ba, cpw, ls);
    outproj_gemm<<<dim3(BATCH * SEQ / 64, 2), 256, 0, stream>>>(
        cpw, ls, Wot, bo, x, (float*)d_out);
}

// Round 11
// 250.527 us; speedup vs baseline: 1.2284x; 1.0602x over previous
//
#include <hip/hip_runtime.h>
#include <hip/hip_bf16.h>

// GraphTransformerLayer: B=8, N=1024, E=256, H=8, D=32, C=4 (all fp32 in/out)
#define BATCH 8
#define SEQ   1024
#define EMB   256
#define NH    8
#define HD    32
#define QSCALE 0.2550030053f   // log2(e)/sqrt(32), folded into Wq/bq

typedef __attribute__((ext_vector_type(8))) short short8;
typedef __attribute__((ext_vector_type(4))) float floatx4;

__device__ __forceinline__ ushort f2bf(float f) {
    __hip_bfloat16 h = __float2bfloat16(f);
    return *reinterpret_cast<ushort*>(&h);
}

__device__ __forceinline__ float bf2f(ushort u) {
    unsigned v = ((unsigned)u) << 16;
    return __builtin_bit_cast(float, v);
}

// async 16B/lane global->LDS DMA: each lane loads 16B from its own global
// address into wave-uniform LDS base + lane*16 (m97/m104 semantics).
__device__ __forceinline__ void gload_lds16(const float4* g, float4* l) {
    __builtin_amdgcn_global_load_lds(
        (const __attribute__((address_space(1))) unsigned int*)g,
        (__attribute__((address_space(3))) unsigned int*)l, 16, 0, 0);
}

// ---------------------------------------------------------------------------
// Frag-packed layouts (R8-R10: line-transactions-per-instruction is THE
// bottleneck; every GEMM operand loads/stores base + lane*8):
//   W (all 4):  [c/16][ks][quad][l16][8]
//   x packed:   [n/16][ks][quad][l16][8]
//   Q,K:        [bh][n/16][d/8][n%16][d%8]
//   V:          [bh][key/32][d/16][sg][d%16][si]  (quad-interleaved slots)
//   cp:         [tile=n/16][h][l16=n%16][d%32]
// ---------------------------------------------------------------------------

// Kernel 0: prep. blocks 0..255: transpose+pack Wq,Wk,Wv,Wo (Wq pre-scaled
// by log2(e)/sqrt(32)). blocks 256..767: pack x -> bf16 frag layout.
__global__ __launch_bounds__(256) void prep_kernel(
    const float* __restrict__ Wq, const float* __restrict__ Wk,
    const float* __restrict__ Wv, const float* __restrict__ Wo,
    const float* __restrict__ x,
    ushort* __restrict__ Wqt, ushort* __restrict__ Wkt,
    ushort* __restrict__ Wvt, ushort* __restrict__ Wot,
    ushort* __restrict__ xb)
{
    const int blk = blockIdx.x;
    if (blk < 256) {
        __shared__ float tilebuf[32][33];
        const int mat = blk >> 6, tile = blk & 63;
        const int ti = tile >> 3, tj = tile & 7;     // ti: k-tile, tj: n-tile
        const float* W = (mat == 0) ? Wq : (mat == 1) ? Wk : (mat == 2) ? Wv : Wo;
        ushort* Wt = (mat == 0) ? Wqt : (mat == 1) ? Wkt : (mat == 2) ? Wvt : Wot;
        const float scale = (mat == 0) ? QSCALE : 1.0f;

        const int tx = threadIdx.x & 31, ty = threadIdx.x >> 5;  // 32 x 8
        #pragma unroll
        for (int p = 0; p < 4; ++p)
            tilebuf[ty + p * 8][tx] = W[(size_t)(ti * 32 + ty + p * 8) * EMB + tj * 32 + tx];
        __syncthreads();
        #pragma unroll
        for (int p = 0; p < 4; ++p) {
            const int n = tj * 32 + ty + p * 8;      // output col
            const int k = ti * 32 + tx;              // input dim
            Wt[(size_t)(n >> 4) * 4096 + (k >> 5) * 512 + ((k >> 3) & 3) * 128
               + (n & 15) * 8 + (k & 7)] = f2bf(tilebuf[tx][ty + p * 8] * scale);
        }
    } else {
        const int tile = blk - 256;                  // 0..511 row-tiles of x
        const float* __restrict__ xs = x + (size_t)tile * 16 * EMB;
        ushort* __restrict__ xd = xb + (size_t)tile * 4096;
        #pragma unroll
        for (int j = 0; j < 16; ++j) {
            const int o = j * 256 + threadIdx.x;     // packed offset in tile
            const int ks = o >> 9, quad = (o >> 7) & 3, l16 = (o >> 3) & 15, e = o & 7;
            xd[o] = f2bf(xs[(size_t)l16 * EMB + ks * 32 + quad * 8 + e]);
        }
    }
}

// ---------------------------------------------------------------------------
// Kernel 1: QKV projection as MFMA GEMM (grid (128,3), acc[16]).
// R11: for Q,K the MFMA operands are SWAPPED (mfma(W, x)) so the accumulator
// is transposed: lane l16 = token, r = column. One thread's acc[i][0..3] is
// then 4 consecutive d in the packed Q/K layout -> ONE aligned ushort4 store
// (was 64 scalar 2B stores scattering 16 lines each — the same TA signature
// that cost attn 3x in R8). Identical product multisets, identical k-order
// -> bit-identical fp32. V keeps the original orientation (its epilogue
// needs key-consecutive registers; already half-dense stores).
// ---------------------------------------------------------------------------
__global__ __launch_bounds__(256) void qkv_gemm(
    const ushort* __restrict__ xb,
    const ushort* __restrict__ Wqt, const ushort* __restrict__ Wkt,
    const ushort* __restrict__ Wvt,
    const float* __restrict__ bq, const float* __restrict__ bk,
    const float* __restrict__ bv,
    ushort* __restrict__ Qb, ushort* __restrict__ Kb, ushort* __restrict__ Vt)
{
    const int mat = blockIdx.y;
    const ushort* __restrict__ Wt = (mat == 0) ? Wqt : (mat == 1) ? Wkt : Wvt;
    const float* __restrict__ bias = (mat == 0) ? bq : (mat == 1) ? bk : bv;
    const float bscale = (mat == 0) ? QSCALE : 1.0f;

    const int w = threadIdx.x >> 6, lane = threadIdx.x & 63;
    const int quad = lane >> 4, l16 = lane & 15;
    const int row0 = blockIdx.x * 64 + w * 16;

    floatx4 acc[16];
    #pragma unroll
    for (int i = 0; i < 16; ++i) acc[i] = (floatx4){0.f, 0.f, 0.f, 0.f};

    const ushort* __restrict__ xrow = xb + (size_t)(blockIdx.x * 4 + w) * 4096 + lane * 8;
    const ushort* __restrict__ wrow = Wt + lane * 8;

    if (mat < 2) {
        // swapped orientation: acc[i][r] = (c = i*16 + quad*4 + r, n = row0+l16)
        #pragma unroll
        for (int ks = 0; ks < 8; ++ks) {
            const short8 a = *(const short8*)(xrow + ks * 512);
            #pragma unroll
            for (int i = 0; i < 16; ++i) {
                const short8 bf = *(const short8*)(wrow + (size_t)i * 4096 + ks * 512);
                acc[i] = __builtin_amdgcn_mfma_f32_16x16x32_bf16(bf, a, acc[i], 0, 0, 0);
            }
        }
        ushort* __restrict__ dst = (mat == 0) ? Qb : Kb;
        const int tile = blockIdx.x * 4 + w;     // n >> 4 (same for all 16 rows)
        const int b = row0 >> 10;
        #pragma unroll
        for (int i = 0; i < 16; ++i) {
            const int c0i = i * 16 + quad * 4;   // column of r=0
            const int h = c0i >> 5;              // = i>>1, uniform over quad*4+r
            const int d0 = c0i & (HD - 1);
            const float4 bb4 = *(const float4*)(bias + c0i);
            ushort4 t4;
            t4.x = f2bf(acc[i][0] + bb4.x * bscale);
            t4.y = f2bf(acc[i][1] + bb4.y * bscale);
            t4.z = f2bf(acc[i][2] + bb4.z * bscale);
            t4.w = f2bf(acc[i][3] + bb4.w * bscale);
            // packed: [bh][tile][d>>3][n&15][d&7]; d0&7 in {0,4} -> 8B aligned
            *(ushort4*)(dst + (size_t)(b * NH + h) * SEQ * HD + (size_t)tile * 512
                        + (d0 >> 3) * 128 + l16 * 8 + (d0 & 7)) = t4;
        }
    } else {
        // original orientation: acc[i][r] = (n = row0 + quad*4 + r, c = i*16+l16)
        #pragma unroll
        for (int ks = 0; ks < 8; ++ks) {
            const short8 a = *(const short8*)(xrow + ks * 512);
            #pragma unroll
            for (int i = 0; i < 16; ++i) {
                const short8 bf = *(const short8*)(wrow + (size_t)i * 4096 + ks * 512);
                acc[i] = __builtin_amdgcn_mfma_f32_16x16x32_bf16(a, bf, acc[i], 0, 0, 0);
            }
        }
        const int gr0 = row0 + quad * 4;
        const int b = gr0 >> 10, n0 = gr0 & (SEQ - 1);
        const int keyblk = n0 >> 5, j0 = n0 & 31;
        const int sg = (j0 & 15) >> 2, si0 = (j0 & 16) ? 4 : 0;
        #pragma unroll
        for (int i = 0; i < 16; ++i) {
            const int c = i * 16 + l16, h = c >> 5, d = c & (HD - 1);
            const float bb = bias[c];
            ushort4 t4;
            t4.x = f2bf(acc[i][0] + bb); t4.y = f2bf(acc[i][1] + bb);
            t4.z = f2bf(acc[i][2] + bb); t4.w = f2bf(acc[i][3] + bb);
            // packed: [bh][keyblk][d>>4][sg][d&15][si0..si0+3]
            *(ushort4*)(Vt + (size_t)(b * NH + h) * SEQ * HD + (size_t)keyblk * 1024
                        + (d >> 4) * 512 + sg * 128 + (d & 15) * 8 + si0) = t4;
        }
    }
}

// ---------------------------------------------------------------------------
// Kernel 2: attention, swapped-QK^T — QBLK=32, FROZEN (R10 win): each wave
// computes one head x 32 q-rows (two 16-row fragments A/B sharing the SAME
// K/V frag loads — halves TA instructions and barriers per unit work).
// Plain __syncthreads, depth-1 DMA dbuf, zero inline asm.
// LDS 2*32*65*16 = 66560 B -> 2 blocks/CU, 16 waves/CU.
// ---------------------------------------------------------------------------
__global__ __launch_bounds__(512, 4) void attn_kernel(
    const ushort* __restrict__ Qb, const ushort* __restrict__ Kb,
    const ushort* __restrict__ Vt, const float* __restrict__ adj,
    const float* __restrict__ Wa, const float* __restrict__ ba,
    ushort* __restrict__ cp, float* __restrict__ lsum)
{
    __shared__ float4 Atile[2][32][65];      // +1 float4 row pad (DMA fills [0,64))
    const int tid = threadIdx.x, h = tid >> 6, lane = tid & 63;
    const int quad = lane >> 4, l16 = lane & 15;
    const int q0 = blockIdx.x * 32, b = blockIdx.y, z = blockIdx.z;
    const int bh = b * NH + h;
    const int kz = z * 512;

    const float LOG2E = 1.4426950408889634f;
    const float wa0 = Wa[0 * NH + h] * LOG2E, wa1 = Wa[1 * NH + h] * LOG2E;
    const float wa2 = Wa[2 * NH + h] * LOG2E, wa3 = Wa[3 * NH + h] * LOG2E;
    const float bah = ba[h] * LOG2E;

    // Q frags (B-operand of swapped QK), packed: two coalesced 1KB wave loads
    const ushort* __restrict__ qbase = Qb + (size_t)bh * SEQ * HD + lane * 8;
    const short8 aqA = *(const short8*)(qbase + (size_t)(blockIdx.x * 2)     * 512);
    const short8 aqB = *(const short8*)(qbase + (size_t)(blockIdx.x * 2 + 1) * 512);

    floatx4 oA0 = {0.f, 0.f, 0.f, 0.f}, oA1 = {0.f, 0.f, 0.f, 0.f};
    floatx4 oB0 = {0.f, 0.f, 0.f, 0.f}, oB1 = {0.f, 0.f, 0.f, 0.f};
    float laccA = 0.f, laccB = 0.f;

    const float4* __restrict__ adjb = (const float4*)adj + (size_t)b * SEQ * SEQ;
    // wave h DMAs adj rows 4h..4h+3 of the block's 32-row tile
    const float4* asrc[4];
    #pragma unroll
    for (int p = 0; p < 4; ++p)
        asrc[p] = adjb + (size_t)(q0 + 4 * h + p) * SEQ + kz + lane;

    const ushort* __restrict__ Kbase = Kb + (size_t)bh * SEQ * HD + lane * 8;
    const ushort* __restrict__ Vbase = Vt + (size_t)bh * SEQ * HD + lane * 8;

    // prologue: DMA tile 0
    #pragma unroll
    for (int p = 0; p < 4; ++p)
        gload_lds16(asrc[p], &Atile[0][4 * h + p][0]);
    __syncthreads();   // implicit vmcnt(0) drain -> tile 0 resident

    for (int it = 0; it < 8; ++it) {          // 8 x 64 = 512 keys per split
        const int cur = it & 1;
        const int key0 = kz + it * 64;

        if (it < 7) {                          // async prefetch of next tile
            #pragma unroll
            for (int p = 0; p < 4; ++p)
                gload_lds16(asrc[p] + (it + 1) * 64, &Atile[cur ^ 1][4 * h + p][0]);
        }

        // K frags (A-operand), packed, SHARED by both q-fragments
        const ushort* kp = Kbase + (size_t)(key0 >> 4) * 512;
        const short8 k0 = *(const short8*)(kp);
        const short8 k1 = *(const short8*)(kp + 512);
        const short8 k2 = *(const short8*)(kp + 1024);
        const short8 k3 = *(const short8*)(kp + 1536);
        const floatx4 zz = {0.f, 0.f, 0.f, 0.f};
        floatx4 sA0 = __builtin_amdgcn_mfma_f32_16x16x32_bf16(k0, aqA, zz, 0, 0, 0);
        floatx4 sA1 = __builtin_amdgcn_mfma_f32_16x16x32_bf16(k1, aqA, zz, 0, 0, 0);
        floatx4 sA2 = __builtin_amdgcn_mfma_f32_16x16x32_bf16(k2, aqA, zz, 0, 0, 0);
        floatx4 sA3 = __builtin_amdgcn_mfma_f32_16x16x32_bf16(k3, aqA, zz, 0, 0, 0);
        floatx4 sB0 = __builtin_amdgcn_mfma_f32_16x16x32_bf16(k0, aqB, zz, 0, 0, 0);
        floatx4 sB1 = __builtin_amdgcn_mfma_f32_16x16x32_bf16(k1, aqB, zz, 0, 0, 0);
        floatx4 sB2 = __builtin_amdgcn_mfma_f32_16x16x32_bf16(k2, aqB, zz, 0, 0, 0);
        floatx4 sB3 = __builtin_amdgcn_mfma_f32_16x16x32_bf16(k3, aqB, zz, 0, 0, 0);

        // bias + exp2; lane covers q = l16 (frag A) / 16+l16 (frag B),
        // keys = 16t + 4*quad + r.
        ushort puA0[8], puA1[8], puB0[8], puB1[8];
        #pragma unroll
        for (int r = 0; r < 4; ++r) {
            const int col = 4 * quad + r;
            // frag A: rows l16
            {
                const float4 a0 = Atile[cur][l16][col];
                const float4 a1 = Atile[cur][l16][16 + col];
                const float4 a2 = Atile[cur][l16][32 + col];
                const float4 a3 = Atile[cur][l16][48 + col];
                const float b0 = fmaf(a0.x, wa0, fmaf(a0.y, wa1, fmaf(a0.z, wa2, fmaf(a0.w, wa3, bah))));
                const float b1 = fmaf(a1.x, wa0, fmaf(a1.y, wa1, fmaf(a1.z, wa2, fmaf(a1.w, wa3, bah))));
                const float b2 = fmaf(a2.x, wa0, fmaf(a2.y, wa1, fmaf(a2.z, wa2, fmaf(a2.w, wa3, bah))));
                const float b3 = fmaf(a3.x, wa0, fmaf(a3.y, wa1, fmaf(a3.z, wa2, fmaf(a3.w, wa3, bah))));
                const float p0 = __builtin_amdgcn_exp2f(sA0[r] + b0);
                const float p1 = __builtin_amdgcn_exp2f(sA1[r] + b1);
                const float p2 = __builtin_amdgcn_exp2f(sA2[r] + b2);
                const float p3 = __builtin_amdgcn_exp2f(sA3[r] + b3);
                laccA += (p0 + p1) + (p2 + p3);
                puA0[r] = f2bf(p0); puA0[4 + r] = f2bf(p1);
                puA1[r] = f2bf(p2); puA1[4 + r] = f2bf(p3);
            }
            // frag B: rows 16+l16
            {
                const float4 a0 = Atile[cur][16 + l16][col];
                const float4 a1 = Atile[cur][16 + l16][16 + col];
                const float4 a2 = Atile[cur][16 + l16][32 + col];
                const float4 a3 = Atile[cur][16 + l16][48 + col];
                const float b0 = fmaf(a0.x, wa0, fmaf(a0.y, wa1, fmaf(a0.z, wa2, fmaf(a0.w, wa3, bah))));
                const float b1 = fmaf(a1.x, wa0, fmaf(a1.y, wa1, fmaf(a1.z, wa2, fmaf(a1.w, wa3, bah))));
                const float b2 = fmaf(a2.x, wa0, fmaf(a2.y, wa1, fmaf(a2.z, wa2, fmaf(a2.w, wa3, bah))));
                const float b3 = fmaf(a3.x, wa0, fmaf(a3.y, wa1, fmaf(a3.z, wa2, fmaf(a3.w, wa3, bah))));
                const float p0 = __builtin_amdgcn_exp2f(sB0[r] + b0);
                const float p1 = __builtin_amdgcn_exp2f(sB1[r] + b1);
                const float p2 = __builtin_amdgcn_exp2f(sB2[r] + b2);
                const float p3 = __builtin_amdgcn_exp2f(sB3[r] + b3);
                laccB += (p0 + p1) + (p2 + p3);
                puB0[r] = f2bf(p0); puB0[4 + r] = f2bf(p1);
                puB1[r] = f2bf(p2); puB1[4 + r] = f2bf(p3);
            }
        }
        const short8 pfA0 = *(const short8*)puA0;
        const short8 pfA1 = *(const short8*)puA1;
        const short8 pfB0 = *(const short8*)puB0;
        const short8 pfB1 = *(const short8*)puB1;

        // V frags (A-operand), packed, SHARED by both q-fragments
        const ushort* vp = Vbase + (size_t)(key0 >> 5) * 1024;
        const short8 v00 = *(const short8*)(vp);          // d=l16,    keys blk0
        const short8 v10 = *(const short8*)(vp + 512);    // d=16+l16, keys blk0
        const short8 v01 = *(const short8*)(vp + 1024);   // d=l16,    keys blk1
        const short8 v11 = *(const short8*)(vp + 1536);   // d=16+l16, keys blk1
        oA0 = __builtin_amdgcn_mfma_f32_16x16x32_bf16(v00, pfA0, oA0, 0, 0, 0);
        oA1 = __builtin_amdgcn_mfma_f32_16x16x32_bf16(v10, pfA0, oA1, 0, 0, 0);
        oA0 = __builtin_amdgcn_mfma_f32_16x16x32_bf16(v01, pfA1, oA0, 0, 0, 0);
        oA1 = __builtin_amdgcn_mfma_f32_16x16x32_bf16(v11, pfA1, oA1, 0, 0, 0);
        oB0 = __builtin_amdgcn_mfma_f32_16x16x32_bf16(v00, pfB0, oB0, 0, 0, 0);
        oB1 = __builtin_amdgcn_mfma_f32_16x16x32_bf16(v10, pfB0, oB1, 0, 0, 0);
        oB0 = __builtin_amdgcn_mfma_f32_16x16x32_bf16(v01, pfB1, oB0, 0, 0, 0);
        oB1 = __builtin_amdgcn_mfma_f32_16x16x32_bf16(v11, pfB1, oB1, 0, 0, 0);

        __syncthreads();   // all waves done with Atile[cur]; next DMA arrived
    }

    // key dim is lane-local; only the quad (key-block) reduction remains
    laccA += __shfl_xor(laccA, 16, 64);
    laccA += __shfl_xor(laccA, 32, 64);
    laccB += __shfl_xor(laccB, 16, 64);
    laccB += __shfl_xor(laccB, 32, 64);

    ushort* __restrict__ cpz = cp + (size_t)z * BATCH * SEQ * EMB;
    float* __restrict__ lsz = lsum + (size_t)z * BATCH * SEQ * NH;
    // packed cp: [tile][h][l16][d%32]; lane holds d = 4*quad + r (+16)
    const size_t tA = ((size_t)b * 64 + blockIdx.x * 2)     * 4096 + (size_t)h * 512
                    + l16 * 32 + 4 * quad;
    const size_t tB = ((size_t)b * 64 + blockIdx.x * 2 + 1) * 4096 + (size_t)h * 512
                    + l16 * 32 + 4 * quad;
    ushort4 t;
    t.x = f2bf(oA0[0]); t.y = f2bf(oA0[1]); t.z = f2bf(oA0[2]); t.w = f2bf(oA0[3]);
    *(ushort4*)(cpz + tA)      = t;
    t.x = f2bf(oA1[0]); t.y = f2bf(oA1[1]); t.z = f2bf(oA1[2]); t.w = f2bf(oA1[3]);
    *(ushort4*)(cpz + tA + 16) = t;
    t.x = f2bf(oB0[0]); t.y = f2bf(oB0[1]); t.z = f2bf(oB0[2]); t.w = f2bf(oB0[3]);
    *(ushort4*)(cpz + tB)      = t;
    t.x = f2bf(oB1[0]); t.y = f2bf(oB1[1]); t.z = f2bf(oB1[2]); t.w = f2bf(oB1[3]);
    *(ushort4*)(cpz + tB + 16) = t;
    if (quad == 0) {
        const size_t growA = (size_t)b * SEQ + q0 + l16;
        lsz[growA * NH + h]        = laccA;
        lsz[(growA + 16) * NH + h] = laccB;
    }
}

// ---------------------------------------------------------------------------
// Kernel 3: outproj as MFMA GEMM. A-frags from packed cp — R11: paired
// ushort4 loads merged into single 16B short8 loads (full-line coverage).
// B-frags from packed Wot (lane*8). Combines the two bf16 key-split
// partials (fp32 add), normalizes by l, epilogue + bo + x residual.
// Grid (128,2).
// ---------------------------------------------------------------------------
__global__ __launch_bounds__(256) void outproj_gemm(
    const ushort* __restrict__ cp, const float* __restrict__ lsum,
    const ushort* __restrict__ Wot, const float* __restrict__ bo,
    const float* __restrict__ x, float* __restrict__ out)
{
    const int w = threadIdx.x >> 6, lane = threadIdx.x & 63;
    const int quad = lane >> 4, l16 = lane & 15;
    const int row0 = blockIdx.x * 64 + w * 16;
    const int c0 = blockIdx.y * 128;     // column half
    const int arow = row0 + l16;
    const ushort* __restrict__ cp1 = cp + (size_t)BATCH * SEQ * EMB;
    const float* __restrict__ l1  = lsum + (size_t)BATCH * SEQ * NH;

    // packed cp row base for this wave's 16-row tile
    const size_t tb = (size_t)(blockIdx.x * 4 + w) * 4096 + l16 * 32 + quad * 8;
    const ushort* __restrict__ wrow = Wot + (size_t)(c0 >> 4) * 4096 + lane * 8;

    floatx4 acc[8];
    #pragma unroll
    for (int i = 0; i < 8; ++i) acc[i] = (floatx4){0.f, 0.f, 0.f, 0.f};

    #pragma unroll
    for (int ks = 0; ks < 8; ++ks) {
        const float invl = 1.0f / (lsum[(size_t)arow * NH + ks] + l1[(size_t)arow * NH + ks]);
        const short8 cc0 = *(const short8*)(cp  + tb + ks * 512);
        const short8 cc1 = *(const short8*)(cp1 + tb + ks * 512);
        ushort au[8];
        #pragma unroll
        for (int j = 0; j < 8; ++j)
            au[j] = f2bf((bf2f((ushort)cc0[j]) + bf2f((ushort)cc1[j])) * invl);
        const short8 a = *(const short8*)au;
        #pragma unroll
        for (int i = 0; i < 8; ++i) {
            const short8 bfr = *(const short8*)(wrow + (size_t)i * 4096 + ks * 512);
            acc[i] = __builtin_amdgcn_mfma_f32_16x16x32_bf16(a, bfr, acc[i], 0, 0, 0);
        }
    }

    const int gr0 = row0 + quad * 4;
    #pragma unroll
    for (int i = 0; i < 8; ++i) {
        const int c = c0 + i * 16 + l16;
        const float bov = bo[c];
        #pragma unroll
        for (int r = 0; r < 4; ++r) {
            const size_t idx = (size_t)(gr0 + r) * EMB + c;
            out[idx] = acc[i][r] + bov + x[idx];
        }
    }
}

extern "C" void kernel_launch(void* const* d_in, const int* in_sizes, int n_in,
                              void* d_out, int out_size, void* d_ws, size_t ws_size,
                              hipStream_t stream) {
    const float* x   = (const float*)d_in[0];
    const float* adj = (const float*)d_in[1];
    const float* Wq  = (const float*)d_in[2];
    const float* bq  = (const float*)d_in[3];
    const float* Wk  = (const float*)d_in[4];
    const float* bk  = (const float*)d_in[5];
    const float* Wv  = (const float*)d_in[6];
    const float* bv  = (const float*)d_in[7];
    const float* Wo  = (const float*)d_in[8];
    const float* bo  = (const float*)d_in[9];
    const float* Wa  = (const float*)d_in[10];
    const float* ba  = (const float*)d_in[11];

    const size_t per = (size_t)BATCH * NH * SEQ * HD;   // 2,097,152
    ushort* Qb  = (ushort*)d_ws;
    ushort* Kb  = Qb + per;
    ushort* Vt  = Kb + per;
    ushort* Wqt = Vt + per;
    ushort* Wkt = Wqt + EMB * EMB;
    ushort* Wvt = Wkt + EMB * EMB;
    ushort* Wot = Wvt + EMB * EMB;
    ushort* cpw = Wot + EMB * EMB;                      // 2 x 4 MB bf16
    ushort* xbp = cpw + 2 * (size_t)BATCH * SEQ * EMB;  // 4 MB bf16 packed x
    float*  ls  = (float*)(xbp + (size_t)BATCH * SEQ * EMB);  // 2 x 256 KB

    prep_kernel<<<768, 256, 0, stream>>>(Wq, Wk, Wv, Wo, x,
                                         Wqt, Wkt, Wvt, Wot, xbp);
    qkv_gemm<<<dim3(BATCH * SEQ / 64, 3), 256, 0, stream>>>(
        xbp, Wqt, Wkt, Wvt, bq, bk, bv, Qb, Kb, Vt);
    attn_kernel<<<dim3(SEQ / 32, BATCH, 2), 512, 0, stream>>>(
        Qb, Kb, Vt, adj, Wa, ba, cpw, ls);
    outproj_gemm<<<dim3(BATCH * SEQ / 64, 2), 256, 0, stream>>>(
        cpw, ls, Wot, bo, x, (float*)d_out);
}